// Round 2
// baseline (562.360 us; speedup 1.0000x reference)
//
#include <hip/hip_runtime.h>
#include <hip/hip_bf16.h>
#include <math.h>

#define N_NODES 16384
#define C_IN 32

typedef __attribute__((ext_vector_type(8))) short short8;
typedef __attribute__((ext_vector_type(4))) float f32x4;

__device__ __forceinline__ unsigned short f2bf(float f) {
    unsigned u = __float_as_uint(f);
    u = u + 0x7fffu + ((u >> 16) & 1u);   // RNE to bf16
    return (unsigned short)(u >> 16);
}

// ---------------------------------------------------------------------------
// K0: zero gc[32] + total[1] (contiguous 33 floats)
// ---------------------------------------------------------------------------
__global__ void k_zero(float* __restrict__ p) {
    p[threadIdx.x] = 0.f;
}

// ---------------------------------------------------------------------------
// K1: attention scores.  8 nodes per 256-thread block.
//     h1 = relu(x@a_w1+b1); h2 = relu(h1@a_w2+b2); s = h2@a_w3+b3
// ---------------------------------------------------------------------------
__global__ __launch_bounds__(256) void k_attn_scores(
    const float* __restrict__ x,
    const float* __restrict__ aw1, const float* __restrict__ ab1,
    const float* __restrict__ aw2, const float* __restrict__ ab2,
    const float* __restrict__ aw3, const float* __restrict__ ab3,
    float* __restrict__ scores)
{
    __shared__ float w1s[4096];   // [32][128]
    __shared__ float w2s[8192];   // [128][64]
    __shared__ float b1s[128];
    __shared__ float b2s[64];
    __shared__ float w3s[64];
    __shared__ float xs[256];     // 8 nodes x 32 ch
    __shared__ float h1s[1024];   // 8 nodes x 128
    __shared__ float ps[256];     // partials

    const int tid = threadIdx.x;
    for (int i = tid; i < 4096; i += 256) w1s[i] = aw1[i];
    for (int i = tid; i < 8192; i += 256) w2s[i] = aw2[i];
    if (tid < 128) b1s[tid] = ab1[tid];
    if (tid < 64)  { b2s[tid] = ab2[tid]; w3s[tid] = aw3[tid]; }
    xs[tid] = x[(size_t)blockIdx.x * 256 + tid];
    __syncthreads();

    const int nl  = tid >> 5;   // node 0..7
    const int t31 = tid & 31;

    // layer 1: each thread computes 4 strided h1 outputs (bank-conflict-free)
    float acc0 = b1s[t31], acc1 = b1s[t31+32], acc2 = b1s[t31+64], acc3 = b1s[t31+96];
    #pragma unroll
    for (int c = 0; c < 32; ++c) {
        float xv = xs[nl*32 + c];
        const float* wr = &w1s[c*128 + t31];
        acc0 += xv * wr[0];
        acc1 += xv * wr[32];
        acc2 += xv * wr[64];
        acc3 += xv * wr[96];
    }
    h1s[nl*128 + t31]      = fmaxf(acc0, 0.f);
    h1s[nl*128 + t31 + 32] = fmaxf(acc1, 0.f);
    h1s[nl*128 + t31 + 64] = fmaxf(acc2, 0.f);
    h1s[nl*128 + t31 + 96] = fmaxf(acc3, 0.f);
    __syncthreads();

    // layer 2 + dot with w3: each thread does 2 h2 outputs
    float a0 = b2s[t31], a1 = b2s[t31 + 32];
    #pragma unroll 8
    for (int o = 0; o < 128; ++o) {
        float hv = h1s[nl*128 + o];        // broadcast (2 nodes/wave: 2-way, free)
        a0 += hv * w2s[o*64 + t31];
        a1 += hv * w2s[o*64 + t31 + 32];
    }
    ps[tid] = fmaxf(a0, 0.f) * w3s[t31] + fmaxf(a1, 0.f) * w3s[t31 + 32];
    __syncthreads();
    if (tid < 8) {
        float s = ab3[0];
        #pragma unroll
        for (int k = 0; k < 32; ++k) s += ps[tid*32 + k];
        scores[(size_t)blockIdx.x * 8 + tid] = s;
    }
}

// ---------------------------------------------------------------------------
// K2: softmax max + sum(exp) over 16384 scores, single block
// ---------------------------------------------------------------------------
__global__ __launch_bounds__(1024) void k_softmax_red(
    const float* __restrict__ scores, float* __restrict__ red)
{
    __shared__ float sm[1024];
    const int tid = threadIdx.x;
    float m = -3.4e38f;
    for (int i = tid; i < N_NODES; i += 1024) m = fmaxf(m, scores[i]);
    sm[tid] = m; __syncthreads();
    for (int s = 512; s > 0; s >>= 1) {
        if (tid < s) sm[tid] = fmaxf(sm[tid], sm[tid + s]);
        __syncthreads();
    }
    m = sm[0];
    __syncthreads();
    float acc = 0.f;
    for (int i = tid; i < N_NODES; i += 1024) acc += expf(scores[i] - m);
    sm[tid] = acc; __syncthreads();
    for (int s = 512; s > 0; s >>= 1) {
        if (tid < s) sm[tid] += sm[tid + s];
        __syncthreads();
    }
    if (tid == 0) { red[0] = m; red[1] = sm[0]; }
}

// ---------------------------------------------------------------------------
// K3: attn = softmax(scores); wfT(bf16, transposed [32][16384]); gc = sum(wf)
// ---------------------------------------------------------------------------
__global__ __launch_bounds__(256) void k_attn_wf(
    const float* __restrict__ scores, const float* __restrict__ red,
    const float* __restrict__ x, float* __restrict__ attn,
    unsigned short* __restrict__ wfT, float* __restrict__ gc)
{
    const int n = blockIdx.x * 256 + threadIdx.x;
    const float m = red[0], s = red[1];
    const float a = expf(scores[n] - m) / s;
    attn[n] = a;

    float wv[32];
    const float4* xr = (const float4*)(x + (size_t)n * 32);
    #pragma unroll
    for (int q = 0; q < 8; ++q) {
        float4 v = xr[q];
        wv[q*4+0] = v.x * a; wv[q*4+1] = v.y * a;
        wv[q*4+2] = v.z * a; wv[q*4+3] = v.w * a;
    }
    #pragma unroll
    for (int c = 0; c < 32; ++c)
        wfT[(size_t)c * N_NODES + n] = f2bf(wv[c]);   // coalesced per c

    const int lane = threadIdx.x & 63;
    #pragma unroll
    for (int c = 0; c < 32; ++c) {
        float v = wv[c];
        v += __shfl_xor(v, 1);  v += __shfl_xor(v, 2);  v += __shfl_xor(v, 4);
        v += __shfl_xor(v, 8);  v += __shfl_xor(v, 16); v += __shfl_xor(v, 32);
        if (lane == 0) atomicAdd(&gc[c], v);
    }
}

// ---------------------------------------------------------------------------
// K5: total = sum_i dot(AW[i,:], wf[i,:]) with AW = A @ WF, via bf16 MFMA.
//     Block = 4 waves x 16 rows = 64 rows; 8-way K split (2048 cols each).
//     A fp32 -> bf16 in registers; B fragments from L2-resident wfT.
// ---------------------------------------------------------------------------
__global__ __launch_bounds__(256) void k_context(
    const float* __restrict__ A, const unsigned short* __restrict__ wfT,
    const float* __restrict__ x, const float* __restrict__ attn,
    float* __restrict__ total)
{
    const int tid  = threadIdx.x;
    const int wid  = tid >> 6, lane = tid & 63;
    const int rb   = blockIdx.x & 255;   // 256 row-blocks of 64 rows
    const int js   = blockIdx.x >> 8;    // 8 K-splits of 2048
    const int i0   = rb * 64 + wid * 16;
    const int arow = i0 + (lane & 15);
    const int kb   = (lane >> 4) * 8;

    const float*          Ap  = A   + (size_t)arow * N_NODES + js * 2048 + kb;
    const unsigned short* b0p = wfT + (size_t)(lane & 15) * N_NODES + js * 2048 + kb;
    const unsigned short* b1p = b0p + (size_t)16 * N_NODES;

    f32x4 acc0 = {0.f, 0.f, 0.f, 0.f};
    f32x4 acc1 = {0.f, 0.f, 0.f, 0.f};

    #pragma unroll 4
    for (int jj = 0; jj < 2048; jj += 32) {
        float4 f0 = *(const float4*)(Ap + jj);
        float4 f1 = *(const float4*)(Ap + jj + 4);
        short8 av;
        av[0] = (short)f2bf(f0.x); av[1] = (short)f2bf(f0.y);
        av[2] = (short)f2bf(f0.z); av[3] = (short)f2bf(f0.w);
        av[4] = (short)f2bf(f1.x); av[5] = (short)f2bf(f1.y);
        av[6] = (short)f2bf(f1.z); av[7] = (short)f2bf(f1.w);
        short8 b0 = *(const short8*)(b0p + jj);
        short8 b1 = *(const short8*)(b1p + jj);
        acc0 = __builtin_amdgcn_mfma_f32_16x16x32_bf16(av, b0, acc0, 0, 0, 0);
        acc1 = __builtin_amdgcn_mfma_f32_16x16x32_bf16(av, b1, acc1, 0, 0, 0);
    }

    // epilogue: D[row=(lane>>4)*4+r, col=lane&15]; dot with wf = x*attn, reduce
    float partial = 0.f;
    const int cg = lane >> 4, c0 = lane & 15;
    #pragma unroll
    for (int r = 0; r < 4; ++r) {
        const int i = i0 + cg * 4 + r;
        const float a = attn[i];
        partial += acc0[r] * (x[(size_t)i * 32 + c0]      * a);
        partial += acc1[r] * (x[(size_t)i * 32 + 16 + c0] * a);
    }
    partial += __shfl_xor(partial, 1);  partial += __shfl_xor(partial, 2);
    partial += __shfl_xor(partial, 4);  partial += __shfl_xor(partial, 8);
    partial += __shfl_xor(partial, 16); partial += __shfl_xor(partial, 32);
    if (lane == 0) atomicAdd(total, partial);
}

// ---------------------------------------------------------------------------
// K6a: h1 for both gc and gc2 = gc + 0.001*(total/N)
// ---------------------------------------------------------------------------
__global__ __launch_bounds__(1024) void k_mlp1(
    const float* __restrict__ gc, const float* __restrict__ total,
    const float* __restrict__ w1, const float* __restrict__ b1,
    float* __restrict__ h1ab)
{
    __shared__ float g1[32], g2[32];
    const int t = threadIdx.x;
    if (t < 32) {
        float cs = total[0] * (1.0f / 16384.0f);
        g1[t] = gc[t];
        g2[t] = gc[t] + 0.001f * cs;
    }
    __syncthreads();
    float s1 = b1[t], s2 = b1[t];
    #pragma unroll
    for (int c = 0; c < 32; ++c) {
        float wv = w1[(size_t)c * 1024 + t];
        s1 += g1[c] * wv;
        s2 += g2[c] * wv;
    }
    h1ab[t]        = fmaxf(s1, 0.f);
    h1ab[1024 + t] = fmaxf(s2, 0.f);
}

// ---------------------------------------------------------------------------
// K6b: h2 = relu(h1 @ w2 + b2), 16 blocks (2 variants x 8 column slices)
// ---------------------------------------------------------------------------
__global__ __launch_bounds__(128) void k_mlp2(
    const float* __restrict__ h1ab, const float* __restrict__ w2,
    const float* __restrict__ b2, float* __restrict__ h2ab)
{
    const int v = blockIdx.x & 1, sl = blockIdx.x >> 1;
    const int t = sl * 128 + threadIdx.x;
    const float* h = h1ab + v * 1024;
    float acc = b2[t];
    #pragma unroll 8
    for (int mI = 0; mI < 1024; ++mI)
        acc += h[mI] * w2[(size_t)mI * 1024 + t];
    h2ab[v * 1024 + t] = fmaxf(acc, 0.f);
}

// ---------------------------------------------------------------------------
// K6c: out = relu(h2a@w3+b3) + 0.001*relu(h2b@w3+b3) + 0.001*relu(h2b@w3+b3)
// ---------------------------------------------------------------------------
__global__ __launch_bounds__(64) void k_mlp3(
    const float* __restrict__ h2ab, const float* __restrict__ w3,
    const float* __restrict__ b3, float* __restrict__ out)
{
    const int o = blockIdx.x * 64 + threadIdx.x;
    float aa = b3[o], ab_ = b3[o];
    const float* h2a = h2ab;
    const float* h2b = h2ab + 1024;
    #pragma unroll 4
    for (int mI = 0; mI < 1024; ++mI) {
        float wv = w3[(size_t)mI * 256 + o];
        aa  += h2a[mI] * wv;
        ab_ += h2b[mI] * wv;
    }
    float ra = fmaxf(aa, 0.f), rb = fmaxf(ab_, 0.f);
    out[o] = ra + 0.001f * rb + 0.001f * rb;
}

// ---------------------------------------------------------------------------
extern "C" void kernel_launch(void* const* d_in, const int* in_sizes, int n_in,
                              void* d_out, int out_size, void* d_ws, size_t ws_size,
                              hipStream_t stream)
{
    const float* x   = (const float*)d_in[0];
    const float* A   = (const float*)d_in[1];
    const float* gw1 = (const float*)d_in[2];
    const float* gb1 = (const float*)d_in[3];
    const float* gw2 = (const float*)d_in[4];
    const float* gb2 = (const float*)d_in[5];
    const float* gw3 = (const float*)d_in[6];
    const float* gb3 = (const float*)d_in[7];
    const float* aw1 = (const float*)d_in[8];
    const float* ab1 = (const float*)d_in[9];
    const float* aw2 = (const float*)d_in[10];
    const float* ab2 = (const float*)d_in[11];
    const float* aw3 = (const float*)d_in[12];
    const float* ab3 = (const float*)d_in[13];
    float* out = (float*)d_out;

    char* ws = (char*)d_ws;
    float* scores = (float*)(ws + 0);            // 16384 f32
    float* attn   = (float*)(ws + 65536);        // 16384 f32
    float* red    = (float*)(ws + 131072);       // 2 f32 (max, sumexp)
    float* gc     = (float*)(ws + 131328);       // 32 f32, then total (contiguous)
    float* total  = (float*)(ws + 131456);       // 1 f32
    float* h1ab   = (float*)(ws + 131584);       // 2048 f32
    float* h2ab   = (float*)(ws + 139776);       // 2048 f32
    unsigned short* wfT = (unsigned short*)(ws + 262144);  // 32*16384 bf16 = 1 MB

    k_zero       <<<1,    33,   0, stream>>>(gc);
    k_attn_scores<<<N_NODES/8, 256, 0, stream>>>(x, aw1, ab1, aw2, ab2, aw3, ab3, scores);
    k_softmax_red<<<1,    1024, 0, stream>>>(scores, red);
    k_attn_wf    <<<N_NODES/256, 256, 0, stream>>>(scores, red, x, attn, wfT, gc);
    k_context    <<<2048, 256,  0, stream>>>(A, wfT, x, attn, total);
    k_mlp1       <<<1,    1024, 0, stream>>>(gc, total, gw1, gb1, h1ab);
    k_mlp2       <<<16,   128,  0, stream>>>(h1ab, gw2, gb2, h2ab);
    k_mlp3       <<<4,    64,   0, stream>>>(h2ab, gw3, gb3, out);
}

// Round 4
// 415.088 us; speedup vs baseline: 1.3548x; 1.3548x over previous
//
#include <hip/hip_runtime.h>
#include <hip/hip_bf16.h>
#include <math.h>

#define N_NODES 16384
#define C_IN 32

typedef __attribute__((ext_vector_type(8))) short short8;
typedef __attribute__((ext_vector_type(4))) float f32x4;
typedef __attribute__((ext_vector_type(4))) float f4v;

__device__ __forceinline__ unsigned short f2bf(float f) {
    unsigned u = __float_as_uint(f);
    u = u + 0x7fffu + ((u >> 16) & 1u);   // RNE to bf16
    return (unsigned short)(u >> 16);
}

// ---------------------------------------------------------------------------
// K0: zero gc[32] + total[1] (contiguous 33 floats)
// ---------------------------------------------------------------------------
__global__ void k_zero(float* __restrict__ p) {
    p[threadIdx.x] = 0.f;
}

// ---------------------------------------------------------------------------
// K1: attention scores.  8 nodes per 256-thread block.
//     layer1: 4 consecutive outputs/thread (float4 LDS reads)
//     layer2: 2 consecutive outputs/thread (float2 LDS reads)
//     score reduce via shfl (32 lanes per node are wave-contiguous)
// ---------------------------------------------------------------------------
__global__ __launch_bounds__(256) void k_attn_scores(
    const float* __restrict__ x,
    const float* __restrict__ aw1, const float* __restrict__ ab1,
    const float* __restrict__ aw2, const float* __restrict__ ab2,
    const float* __restrict__ aw3, const float* __restrict__ ab3,
    float* __restrict__ scores)
{
    __shared__ float w1s[4096];   // [32][128]
    __shared__ float w2s[8192];   // [128][64]
    __shared__ float b1s[128];
    __shared__ float b2s[64];
    __shared__ float w3s[64];
    __shared__ float xs[256];     // 8 nodes x 32 ch
    __shared__ float h1s[1024];   // 8 nodes x 128

    const int tid = threadIdx.x;
    for (int i = tid; i < 4096; i += 256) w1s[i] = aw1[i];
    for (int i = tid; i < 8192; i += 256) w2s[i] = aw2[i];
    if (tid < 128) b1s[tid] = ab1[tid];
    if (tid < 64)  { b2s[tid] = ab2[tid]; w3s[tid] = aw3[tid]; }
    xs[tid] = x[(size_t)blockIdx.x * 256 + tid];
    __syncthreads();

    const int nl  = tid >> 5;   // node 0..7
    const int t31 = tid & 31;

    // layer 1: outputs o = t31*4 + {0..3}
    float a0 = b1s[t31*4+0], a1 = b1s[t31*4+1], a2 = b1s[t31*4+2], a3 = b1s[t31*4+3];
    #pragma unroll
    for (int c = 0; c < 32; ++c) {
        float xv = xs[nl*32 + c];
        float4 w = *(const float4*)&w1s[c*128 + t31*4];
        a0 += xv * w.x; a1 += xv * w.y; a2 += xv * w.z; a3 += xv * w.w;
    }
    *(float4*)&h1s[nl*128 + t31*4] =
        make_float4(fmaxf(a0,0.f), fmaxf(a1,0.f), fmaxf(a2,0.f), fmaxf(a3,0.f));
    __syncthreads();

    // layer 2 + dot with w3: outputs o = t31*2 + {0,1}
    float c0 = b2s[t31*2], c1 = b2s[t31*2 + 1];
    #pragma unroll 8
    for (int o = 0; o < 128; ++o) {
        float hv = h1s[nl*128 + o];
        float2 w = *(const float2*)&w2s[o*64 + t31*2];
        c0 += hv * w.x;
        c1 += hv * w.y;
    }
    float s = fmaxf(c0, 0.f) * w3s[t31*2] + fmaxf(c1, 0.f) * w3s[t31*2 + 1];
    s += __shfl_xor(s, 1);  s += __shfl_xor(s, 2);  s += __shfl_xor(s, 4);
    s += __shfl_xor(s, 8);  s += __shfl_xor(s, 16);
    if (t31 == 0) scores[(size_t)blockIdx.x * 8 + nl] = s + ab3[0];
}

// ---------------------------------------------------------------------------
// K2: softmax max + sum(exp) over 16384 scores, single block
// ---------------------------------------------------------------------------
__global__ __launch_bounds__(1024) void k_softmax_red(
    const float* __restrict__ scores, float* __restrict__ red)
{
    __shared__ float sm[1024];
    const int tid = threadIdx.x;
    float m = -3.4e38f;
    for (int i = tid; i < N_NODES; i += 1024) m = fmaxf(m, scores[i]);
    sm[tid] = m; __syncthreads();
    for (int s = 512; s > 0; s >>= 1) {
        if (tid < s) sm[tid] = fmaxf(sm[tid], sm[tid + s]);
        __syncthreads();
    }
    m = sm[0];
    __syncthreads();
    float acc = 0.f;
    for (int i = tid; i < N_NODES; i += 1024) acc += expf(scores[i] - m);
    sm[tid] = acc; __syncthreads();
    for (int s = 512; s > 0; s >>= 1) {
        if (tid < s) sm[tid] += sm[tid + s];
        __syncthreads();
    }
    if (tid == 0) { red[0] = m; red[1] = sm[0]; }
}

// ---------------------------------------------------------------------------
// K3: attn = softmax(scores); wfT(bf16, transposed [32][16384]); gc = sum(wf)
// ---------------------------------------------------------------------------
__global__ __launch_bounds__(256) void k_attn_wf(
    const float* __restrict__ scores, const float* __restrict__ red,
    const float* __restrict__ x, float* __restrict__ attn,
    unsigned short* __restrict__ wfT, float* __restrict__ gc)
{
    const int n = blockIdx.x * 256 + threadIdx.x;
    const float m = red[0], s = red[1];
    const float a = expf(scores[n] - m) / s;
    attn[n] = a;

    float wv[32];
    const float4* xr = (const float4*)(x + (size_t)n * 32);
    #pragma unroll
    for (int q = 0; q < 8; ++q) {
        float4 v = xr[q];
        wv[q*4+0] = v.x * a; wv[q*4+1] = v.y * a;
        wv[q*4+2] = v.z * a; wv[q*4+3] = v.w * a;
    }
    #pragma unroll
    for (int c = 0; c < 32; ++c)
        wfT[(size_t)c * N_NODES + n] = f2bf(wv[c]);   // coalesced per c

    const int lane = threadIdx.x & 63;
    #pragma unroll
    for (int c = 0; c < 32; ++c) {
        float v = wv[c];
        v += __shfl_xor(v, 1);  v += __shfl_xor(v, 2);  v += __shfl_xor(v, 4);
        v += __shfl_xor(v, 8);  v += __shfl_xor(v, 16); v += __shfl_xor(v, 32);
        if (lane == 0) atomicAdd(&gc[c], v);
    }
}

// ---------------------------------------------------------------------------
// K5: total = sum_i dot(AW[i,:], wf[i,:]) with AW = A @ WF, via bf16 MFMA.
//     Block = 4 waves x 16 rows = 64 rows; 8-way K split (2048 cols each).
//     A fp32 -> bf16 in registers (nontemporal: A is streamed exactly once);
//     B fragments from L2-resident wfT.
// ---------------------------------------------------------------------------
__global__ __launch_bounds__(256) void k_context(
    const float* __restrict__ A, const unsigned short* __restrict__ wfT,
    const float* __restrict__ x, const float* __restrict__ attn,
    float* __restrict__ total)
{
    const int tid  = threadIdx.x;
    const int wid  = tid >> 6, lane = tid & 63;
    const int rb   = blockIdx.x & 255;   // 256 row-blocks of 64 rows
    const int js   = blockIdx.x >> 8;    // 8 K-splits of 2048
    const int i0   = rb * 64 + wid * 16;
    const int arow = i0 + (lane & 15);
    const int kb   = (lane >> 4) * 8;

    const float*          Ap  = A   + (size_t)arow * N_NODES + js * 2048 + kb;
    const unsigned short* b0p = wfT + (size_t)(lane & 15) * N_NODES + js * 2048 + kb;
    const unsigned short* b1p = b0p + (size_t)16 * N_NODES;

    f32x4 acc0 = {0.f, 0.f, 0.f, 0.f};
    f32x4 acc1 = {0.f, 0.f, 0.f, 0.f};

    #pragma unroll 4
    for (int jj = 0; jj < 2048; jj += 32) {
        f4v f0 = __builtin_nontemporal_load((const f4v*)(Ap + jj));
        f4v f1 = __builtin_nontemporal_load((const f4v*)(Ap + jj + 4));
        short8 av;
        av[0] = (short)f2bf(f0[0]); av[1] = (short)f2bf(f0[1]);
        av[2] = (short)f2bf(f0[2]); av[3] = (short)f2bf(f0[3]);
        av[4] = (short)f2bf(f1[0]); av[5] = (short)f2bf(f1[1]);
        av[6] = (short)f2bf(f1[2]); av[7] = (short)f2bf(f1[3]);
        short8 b0 = *(const short8*)(b0p + jj);
        short8 b1 = *(const short8*)(b1p + jj);
        acc0 = __builtin_amdgcn_mfma_f32_16x16x32_bf16(av, b0, acc0, 0, 0, 0);
        acc1 = __builtin_amdgcn_mfma_f32_16x16x32_bf16(av, b1, acc1, 0, 0, 0);
    }

    // epilogue: D[row=(lane>>4)*4+r, col=lane&15]; dot with wf = x*attn, reduce
    float partial = 0.f;
    const int cg = lane >> 4, c0 = lane & 15;
    #pragma unroll
    for (int r = 0; r < 4; ++r) {
        const int i = i0 + cg * 4 + r;
        const float a = attn[i];
        partial += acc0[r] * (x[(size_t)i * 32 + c0]      * a);
        partial += acc1[r] * (x[(size_t)i * 32 + 16 + c0] * a);
    }
    partial += __shfl_xor(partial, 1);  partial += __shfl_xor(partial, 2);
    partial += __shfl_xor(partial, 4);  partial += __shfl_xor(partial, 8);
    partial += __shfl_xor(partial, 16); partial += __shfl_xor(partial, 32);
    if (lane == 0) atomicAdd(total, partial);
}

// ---------------------------------------------------------------------------
// K6a: h1 for both gc and gc2 = gc + 0.001*(total/N)
// ---------------------------------------------------------------------------
__global__ __launch_bounds__(1024) void k_mlp1(
    const float* __restrict__ gc, const float* __restrict__ total,
    const float* __restrict__ w1, const float* __restrict__ b1,
    float* __restrict__ h1ab)
{
    __shared__ float g1[32], g2[32];
    const int t = threadIdx.x;
    if (t < 32) {
        float cs = total[0] * (1.0f / 16384.0f);
        g1[t] = gc[t];
        g2[t] = gc[t] + 0.001f * cs;
    }
    __syncthreads();
    float s1 = b1[t], s2 = b1[t];
    #pragma unroll
    for (int c = 0; c < 32; ++c) {
        float wv = w1[(size_t)c * 1024 + t];
        s1 += g1[c] * wv;
        s2 += g2[c] * wv;
    }
    h1ab[t]        = fmaxf(s1, 0.f);
    h1ab[1024 + t] = fmaxf(s2, 0.f);
}

// ---------------------------------------------------------------------------
// K6b: h2 = relu(h1 @ w2 + b2), split-K.
//     Grid = 2 variants x 64 output-blocks (16 outputs each); 256 threads =
//     16 outputs x 16 K-groups of 64. LDS tree reduce, no atomics.
// ---------------------------------------------------------------------------
__global__ __launch_bounds__(256) void k_mlp2(
    const float* __restrict__ h1ab, const float* __restrict__ w2,
    const float* __restrict__ b2, float* __restrict__ h2ab)
{
    __shared__ float h1s[1024];
    __shared__ float sm[256];
    const int v   = blockIdx.x & 1;
    const int ob  = blockIdx.x >> 1;      // 0..63
    const int tid = threadIdx.x;
    const int o   = tid & 15, g = tid >> 4;
    for (int i = tid; i < 1024; i += 256) h1s[i] = h1ab[v * 1024 + i];
    __syncthreads();
    const float* wp = w2 + (size_t)(g * 64) * 1024 + ob * 16 + o;
    float acc = 0.f;
    #pragma unroll 8
    for (int k = 0; k < 64; ++k)
        acc += h1s[g * 64 + k] * wp[(size_t)k * 1024];
    sm[tid] = acc;
    __syncthreads();
    if (tid < 16) {
        float s = b2[ob * 16 + tid];
        #pragma unroll
        for (int g2 = 0; g2 < 16; ++g2) s += sm[g2 * 16 + tid];
        h2ab[v * 1024 + ob * 16 + tid] = fmaxf(s, 0.f);
    }
}

// ---------------------------------------------------------------------------
// K6c: out = relu(h2a@w3+b3) + 0.002*relu(h2b@w3+b3), split-K, both variants
//     in one block. Grid = 16 blocks x 512 threads (2v x 16 K-groups x 16 o).
// ---------------------------------------------------------------------------
__global__ __launch_bounds__(512) void k_mlp3(
    const float* __restrict__ h2ab, const float* __restrict__ w3,
    const float* __restrict__ b3, float* __restrict__ out)
{
    __shared__ float sm[512];
    const int tid = threadIdx.x;
    const int v   = tid >> 8;
    const int g   = (tid >> 4) & 15;
    const int o   = tid & 15;
    const int ob  = blockIdx.x;           // 16 blocks x 16 outputs
    const float* hp = h2ab + v * 1024 + g * 64;
    const float* wp = w3 + (size_t)(g * 64) * 256 + ob * 16 + o;
    float acc = 0.f;
    #pragma unroll 8
    for (int k = 0; k < 64; ++k)
        acc += hp[k] * wp[(size_t)k * 256];
    sm[tid] = acc;
    __syncthreads();
    if (tid < 16) {
        float pa = b3[ob * 16 + tid], pb = pa;
        #pragma unroll
        for (int g2 = 0; g2 < 16; ++g2) {
            pa += sm[g2 * 16 + tid];
            pb += sm[256 + g2 * 16 + tid];
        }
        out[ob * 16 + tid] = fmaxf(pa, 0.f) + 0.002f * fmaxf(pb, 0.f);
    }
}

// ---------------------------------------------------------------------------
extern "C" void kernel_launch(void* const* d_in, const int* in_sizes, int n_in,
                              void* d_out, int out_size, void* d_ws, size_t ws_size,
                              hipStream_t stream)
{
    const float* x   = (const float*)d_in[0];
    const float* A   = (const float*)d_in[1];
    const float* gw1 = (const float*)d_in[2];
    const float* gb1 = (const float*)d_in[3];
    const float* gw2 = (const float*)d_in[4];
    const float* gb2 = (const float*)d_in[5];
    const float* gw3 = (const float*)d_in[6];
    const float* gb3 = (const float*)d_in[7];
    const float* aw1 = (const float*)d_in[8];
    const float* ab1 = (const float*)d_in[9];
    const float* aw2 = (const float*)d_in[10];
    const float* ab2 = (const float*)d_in[11];
    const float* aw3 = (const float*)d_in[12];
    const float* ab3 = (const float*)d_in[13];
    float* out = (float*)d_out;

    char* ws = (char*)d_ws;
    float* scores = (float*)(ws + 0);            // 16384 f32
    float* attn   = (float*)(ws + 65536);        // 16384 f32
    float* red    = (float*)(ws + 131072);       // 2 f32 (max, sumexp)
    float* gc     = (float*)(ws + 131328);       // 32 f32, then total (contiguous)
    float* total  = (float*)(ws + 131456);       // 1 f32
    float* h1ab   = (float*)(ws + 131584);       // 2048 f32
    float* h2ab   = (float*)(ws + 139776);       // 2048 f32
    unsigned short* wfT = (unsigned short*)(ws + 262144);  // 32*16384 bf16 = 1 MB

    k_zero       <<<1,    33,   0, stream>>>(gc);
    k_attn_scores<<<N_NODES/8, 256, 0, stream>>>(x, aw1, ab1, aw2, ab2, aw3, ab3, scores);
    k_softmax_red<<<1,    1024, 0, stream>>>(scores, red);
    k_attn_wf    <<<N_NODES/256, 256, 0, stream>>>(scores, red, x, attn, wfT, gc);
    k_context    <<<2048, 256,  0, stream>>>(A, wfT, x, attn, total);
    k_mlp1       <<<1,    1024, 0, stream>>>(gc, total, gw1, gb1, h1ab);
    k_mlp2       <<<128,  256,  0, stream>>>(h1ab, gw2, gb2, h2ab);
    k_mlp3       <<<16,   512,  0, stream>>>(h2ab, gw3, gb3, out);
}

// Round 5
// 368.285 us; speedup vs baseline: 1.5270x; 1.1271x over previous
//
#include <hip/hip_runtime.h>
#include <hip/hip_bf16.h>
#include <math.h>

#define N_NODES 16384
#define C_IN 32
#define BK 256            // k_context tile width (cols per stage)

typedef __attribute__((ext_vector_type(8))) short short8;
typedef __attribute__((ext_vector_type(4))) short s16x4;
typedef __attribute__((ext_vector_type(4))) float f32x4;
typedef __attribute__((ext_vector_type(4))) float f4v;

__device__ __forceinline__ unsigned short f2bf(float f) {
    unsigned u = __float_as_uint(f);
    u = u + 0x7fffu + ((u >> 16) & 1u);   // RNE to bf16
    return (unsigned short)(u >> 16);
}

// ---------------------------------------------------------------------------
// K0: zero gc[32] + total[1] (contiguous 33 floats)
// ---------------------------------------------------------------------------
__global__ void k_zero(float* __restrict__ p) {
    p[threadIdx.x] = 0.f;
}

// ---------------------------------------------------------------------------
// K1: attention scores.  8 nodes per 256-thread block.
// ---------------------------------------------------------------------------
__global__ __launch_bounds__(256) void k_attn_scores(
    const float* __restrict__ x,
    const float* __restrict__ aw1, const float* __restrict__ ab1,
    const float* __restrict__ aw2, const float* __restrict__ ab2,
    const float* __restrict__ aw3, const float* __restrict__ ab3,
    float* __restrict__ scores)
{
    __shared__ float w1s[4096];   // [32][128]
    __shared__ float w2s[8192];   // [128][64]
    __shared__ float b1s[128];
    __shared__ float b2s[64];
    __shared__ float w3s[64];
    __shared__ float xs[256];     // 8 nodes x 32 ch
    __shared__ float h1s[1024];   // 8 nodes x 128

    const int tid = threadIdx.x;
    for (int i = tid; i < 4096; i += 256) w1s[i] = aw1[i];
    for (int i = tid; i < 8192; i += 256) w2s[i] = aw2[i];
    if (tid < 128) b1s[tid] = ab1[tid];
    if (tid < 64)  { b2s[tid] = ab2[tid]; w3s[tid] = aw3[tid]; }
    xs[tid] = x[(size_t)blockIdx.x * 256 + tid];
    __syncthreads();

    const int nl  = tid >> 5;   // node 0..7
    const int t31 = tid & 31;

    // layer 1: outputs o = t31*4 + {0..3}
    float a0 = b1s[t31*4+0], a1 = b1s[t31*4+1], a2 = b1s[t31*4+2], a3 = b1s[t31*4+3];
    #pragma unroll
    for (int c = 0; c < 32; ++c) {
        float xv = xs[nl*32 + c];
        float4 w = *(const float4*)&w1s[c*128 + t31*4];
        a0 += xv * w.x; a1 += xv * w.y; a2 += xv * w.z; a3 += xv * w.w;
    }
    *(float4*)&h1s[nl*128 + t31*4] =
        make_float4(fmaxf(a0,0.f), fmaxf(a1,0.f), fmaxf(a2,0.f), fmaxf(a3,0.f));
    __syncthreads();

    // layer 2 + dot with w3: outputs o = t31*2 + {0,1}
    float c0 = b2s[t31*2], c1 = b2s[t31*2 + 1];
    #pragma unroll 8
    for (int o = 0; o < 128; ++o) {
        float hv = h1s[nl*128 + o];
        float2 w = *(const float2*)&w2s[o*64 + t31*2];
        c0 += hv * w.x;
        c1 += hv * w.y;
    }
    float s = fmaxf(c0, 0.f) * w3s[t31*2] + fmaxf(c1, 0.f) * w3s[t31*2 + 1];
    s += __shfl_xor(s, 1);  s += __shfl_xor(s, 2);  s += __shfl_xor(s, 4);
    s += __shfl_xor(s, 8);  s += __shfl_xor(s, 16);
    if (t31 == 0) scores[(size_t)blockIdx.x * 8 + nl] = s + ab3[0];
}

// ---------------------------------------------------------------------------
// K2: softmax max + sum(exp) over 16384 scores, single block
// ---------------------------------------------------------------------------
__global__ __launch_bounds__(1024) void k_softmax_red(
    const float* __restrict__ scores, float* __restrict__ red)
{
    __shared__ float sm[1024];
    const int tid = threadIdx.x;
    float m = -3.4e38f;
    for (int i = tid; i < N_NODES; i += 1024) m = fmaxf(m, scores[i]);
    sm[tid] = m; __syncthreads();
    for (int s = 512; s > 0; s >>= 1) {
        if (tid < s) sm[tid] = fmaxf(sm[tid], sm[tid + s]);
        __syncthreads();
    }
    m = sm[0];
    __syncthreads();
    float acc = 0.f;
    for (int i = tid; i < N_NODES; i += 1024) acc += expf(scores[i] - m);
    sm[tid] = acc; __syncthreads();
    for (int s = 512; s > 0; s >>= 1) {
        if (tid < s) sm[tid] += sm[tid + s];
        __syncthreads();
    }
    if (tid == 0) { red[0] = m; red[1] = sm[0]; }
}

// ---------------------------------------------------------------------------
// K3: attn = softmax(scores); wfT(bf16, transposed [32][16384]); gc = sum(wf)
// ---------------------------------------------------------------------------
__global__ __launch_bounds__(256) void k_attn_wf(
    const float* __restrict__ scores, const float* __restrict__ red,
    const float* __restrict__ x, float* __restrict__ attn,
    unsigned short* __restrict__ wfT, float* __restrict__ gc)
{
    const int n = blockIdx.x * 256 + threadIdx.x;
    const float m = red[0], s = red[1];
    const float a = expf(scores[n] - m) / s;
    attn[n] = a;

    float wv[32];
    const float4* xr = (const float4*)(x + (size_t)n * 32);
    #pragma unroll
    for (int q = 0; q < 8; ++q) {
        float4 v = xr[q];
        wv[q*4+0] = v.x * a; wv[q*4+1] = v.y * a;
        wv[q*4+2] = v.z * a; wv[q*4+3] = v.w * a;
    }
    #pragma unroll
    for (int c = 0; c < 32; ++c)
        wfT[(size_t)c * N_NODES + n] = f2bf(wv[c]);   // coalesced per c

    const int lane = threadIdx.x & 63;
    #pragma unroll
    for (int c = 0; c < 32; ++c) {
        float v = wv[c];
        v += __shfl_xor(v, 1);  v += __shfl_xor(v, 2);  v += __shfl_xor(v, 4);
        v += __shfl_xor(v, 8);  v += __shfl_xor(v, 16); v += __shfl_xor(v, 32);
        if (lane == 0) atomicAdd(&gc[c], v);
    }
}

// ---------------------------------------------------------------------------
// K5: total = sum_i dot(AW[i,:], wf[i,:]), AW = A @ WF, bf16 MFMA.
//     v2: LDS-staged A. Per wave, each stage instruction reads 1KB CONTIGUOUS
//     from one A row (DRAM page-friendly), cvt fp32->bf16 in regs, ds_write
//     into XOR-swizzled [64][256] bf16 tile (2x32KB double buffer).
//     T14 split: issue loads -> compute MFMA on current tile -> write LDS.
//     B fragments direct from L2/L1-resident wfT (identical across waves).
//     FP order identical to v1 (same kk sequence) -> bitwise-same result.
// ---------------------------------------------------------------------------
__global__ __launch_bounds__(256, 2) void k_context(
    const float* __restrict__ A, const unsigned short* __restrict__ wfT,
    const float* __restrict__ x, const float* __restrict__ attn,
    float* __restrict__ total)
{
    __shared__ unsigned short sA[2][64 * BK];   // 32KB each buffer

    const int tid  = threadIdx.x;
    const int wid  = tid >> 6, lane = tid & 63;
    const int rb   = blockIdx.x & 255;   // 256 row-blocks of 64 rows
    const int js   = blockIdx.x >> 8;    // 8 K-splits of 2048 cols
    const int i0   = rb * 64 + wid * 16; // wave's first A row (it stages its own rows)
    const int col0 = js * 2048;

    const int q    = lane >> 4;          // quadrant 0..3
    const int r16  = lane & 15;
    const int lr   = wid * 16 + r16;     // local row for MFMA A-frag
    const int swzR = (r16 & 7) << 4;     // read-side swizzle key (row&7)

    const unsigned short* bp0 = wfT + (size_t)r16 * N_NODES;
    const unsigned short* bp1 = bp0 + (size_t)16 * N_NODES;

    f32x4 acc0 = {0.f, 0.f, 0.f, 0.f};
    f32x4 acc1 = {0.f, 0.f, 0.f, 0.f};

    // ---- prologue: stage tile 0 into buffer 0 ----
    {
        #pragma unroll
        for (int r = 0; r < 16; ++r) {
            f4v v = __builtin_nontemporal_load(
                (const f4v*)(A + (size_t)(i0 + r) * N_NODES + col0 + lane * 4));
            s16x4 w;
            w[0] = (short)f2bf(v[0]); w[1] = (short)f2bf(v[1]);
            w[2] = (short)f2bf(v[2]); w[3] = (short)f2bf(v[3]);
            int off = (wid*16 + r) * (BK*2) + ((lane*8) ^ ((r & 7) << 4));
            *(s16x4*)((char*)sA[0] + off) = w;
        }
    }
    __syncthreads();

    // ---- main loop: 8 tiles of 256 cols ----
    for (int t = 0; t < 8; ++t) {
        const int cur = t & 1;

        // (1) issue next tile's global loads (held in regs through compute)
        f4v ldv[16];
        if (t < 7) {
            const int cnext = col0 + (t + 1) * BK + lane * 4;
            #pragma unroll
            for (int r = 0; r < 16; ++r)
                ldv[r] = __builtin_nontemporal_load(
                    (const f4v*)(A + (size_t)(i0 + r) * N_NODES + cnext));
        }

        // (2) compute current tile: 8 k-slices x 2 channel-halves
        const char* base = (const char*)sA[cur];
        const int  tcol  = col0 + t * BK;
        #pragma unroll
        for (int kk = 0; kk < 8; ++kk) {
            int off = lr * (BK*2) + ((kk*64 + q*16) ^ swzR);
            short8 av = *(const short8*)(base + off);
            int gcol = tcol + kk*32 + q*8;
            short8 b0 = *(const short8*)(bp0 + gcol);
            short8 b1 = *(const short8*)(bp1 + gcol);
            acc0 = __builtin_amdgcn_mfma_f32_16x16x32_bf16(av, b0, acc0, 0, 0, 0);
            acc1 = __builtin_amdgcn_mfma_f32_16x16x32_bf16(av, b1, acc1, 0, 0, 0);
        }

        // (3) convert + write next tile into the other buffer
        if (t < 7) {
            #pragma unroll
            for (int r = 0; r < 16; ++r) {
                s16x4 w;
                w[0] = (short)f2bf(ldv[r][0]); w[1] = (short)f2bf(ldv[r][1]);
                w[2] = (short)f2bf(ldv[r][2]); w[3] = (short)f2bf(ldv[r][3]);
                int off = (wid*16 + r) * (BK*2) + ((lane*8) ^ ((r & 7) << 4));
                *(s16x4*)((char*)sA[cur ^ 1] + off) = w;
            }
        }
        __syncthreads();
    }

    // ---- epilogue: D[row=(lane>>4)*4+r, col=lane&15]; dot with wf, reduce ----
    float partial = 0.f;
    #pragma unroll
    for (int r = 0; r < 4; ++r) {
        const int i = i0 + q * 4 + r;
        const float a = attn[i];
        partial += acc0[r] * (x[(size_t)i * 32 + r16]      * a);
        partial += acc1[r] * (x[(size_t)i * 32 + 16 + r16] * a);
    }
    partial += __shfl_xor(partial, 1);  partial += __shfl_xor(partial, 2);
    partial += __shfl_xor(partial, 4);  partial += __shfl_xor(partial, 8);
    partial += __shfl_xor(partial, 16); partial += __shfl_xor(partial, 32);
    if (lane == 0) atomicAdd(total, partial);
}

// ---------------------------------------------------------------------------
// K6a: h1 for both gc and gc2 = gc + 0.001*(total/N)
// ---------------------------------------------------------------------------
__global__ __launch_bounds__(1024) void k_mlp1(
    const float* __restrict__ gc, const float* __restrict__ total,
    const float* __restrict__ w1, const float* __restrict__ b1,
    float* __restrict__ h1ab)
{
    __shared__ float g1[32], g2[32];
    const int t = threadIdx.x;
    if (t < 32) {
        float cs = total[0] * (1.0f / 16384.0f);
        g1[t] = gc[t];
        g2[t] = gc[t] + 0.001f * cs;
    }
    __syncthreads();
    float s1 = b1[t], s2 = b1[t];
    #pragma unroll
    for (int c = 0; c < 32; ++c) {
        float wv = w1[(size_t)c * 1024 + t];
        s1 += g1[c] * wv;
        s2 += g2[c] * wv;
    }
    h1ab[t]        = fmaxf(s1, 0.f);
    h1ab[1024 + t] = fmaxf(s2, 0.f);
}

// ---------------------------------------------------------------------------
// K6b: h2 = relu(h1 @ w2 + b2), split-K (16 K-groups of 64), LDS tree reduce.
// ---------------------------------------------------------------------------
__global__ __launch_bounds__(256) void k_mlp2(
    const float* __restrict__ h1ab, const float* __restrict__ w2,
    const float* __restrict__ b2, float* __restrict__ h2ab)
{
    __shared__ float h1s[1024];
    __shared__ float sm[256];
    const int v   = blockIdx.x & 1;
    const int ob  = blockIdx.x >> 1;      // 0..63
    const int tid = threadIdx.x;
    const int o   = tid & 15, g = tid >> 4;
    for (int i = tid; i < 1024; i += 256) h1s[i] = h1ab[v * 1024 + i];
    __syncthreads();
    const float* wp = w2 + (size_t)(g * 64) * 1024 + ob * 16 + o;
    float acc = 0.f;
    #pragma unroll 8
    for (int k = 0; k < 64; ++k)
        acc += h1s[g * 64 + k] * wp[(size_t)k * 1024];
    sm[tid] = acc;
    __syncthreads();
    if (tid < 16) {
        float s = b2[ob * 16 + tid];
        #pragma unroll
        for (int g2 = 0; g2 < 16; ++g2) s += sm[g2 * 16 + tid];
        h2ab[v * 1024 + ob * 16 + tid] = fmaxf(s, 0.f);
    }
}

// ---------------------------------------------------------------------------
// K6c: out = relu(h2a@w3+b3) + 0.002*relu(h2b@w3+b3), split-K, both variants.
// ---------------------------------------------------------------------------
__global__ __launch_bounds__(512) void k_mlp3(
    const float* __restrict__ h2ab, const float* __restrict__ w3,
    const float* __restrict__ b3, float* __restrict__ out)
{
    __shared__ float sm[512];
    const int tid = threadIdx.x;
    const int v   = tid >> 8;
    const int g   = (tid >> 4) & 15;
    const int o   = tid & 15;
    const int ob  = blockIdx.x;           // 16 blocks x 16 outputs
    const float* hp = h2ab + v * 1024 + g * 64;
    const float* wp = w3 + (size_t)(g * 64) * 256 + ob * 16 + o;
    float acc = 0.f;
    #pragma unroll 8
    for (int k = 0; k < 64; ++k)
        acc += hp[k] * wp[(size_t)k * 256];
    sm[tid] = acc;
    __syncthreads();
    if (tid < 16) {
        float pa = b3[ob * 16 + tid], pb = pa;
        #pragma unroll
        for (int g2 = 0; g2 < 16; ++g2) {
            pa += sm[g2 * 16 + tid];
            pb += sm[256 + g2 * 16 + tid];
        }
        out[ob * 16 + tid] = fmaxf(pa, 0.f) + 0.002f * fmaxf(pb, 0.f);
    }
}

// ---------------------------------------------------------------------------
extern "C" void kernel_launch(void* const* d_in, const int* in_sizes, int n_in,
                              void* d_out, int out_size, void* d_ws, size_t ws_size,
                              hipStream_t stream)
{
    const float* x   = (const float*)d_in[0];
    const float* A   = (const float*)d_in[1];
    const float* gw1 = (const float*)d_in[2];
    const float* gb1 = (const float*)d_in[3];
    const float* gw2 = (const float*)d_in[4];
    const float* gb2 = (const float*)d_in[5];
    const float* gw3 = (const float*)d_in[6];
    const float* gb3 = (const float*)d_in[7];
    const float* aw1 = (const float*)d_in[8];
    const float* ab1 = (const float*)d_in[9];
    const float* aw2 = (const float*)d_in[10];
    const float* ab2 = (const float*)d_in[11];
    const float* aw3 = (const float*)d_in[12];
    const float* ab3 = (const float*)d_in[13];
    float* out = (float*)d_out;

    char* ws = (char*)d_ws;
    float* scores = (float*)(ws + 0);            // 16384 f32
    float* attn   = (float*)(ws + 65536);        // 16384 f32
    float* red    = (float*)(ws + 131072);       // 2 f32 (max, sumexp)
    float* gc     = (float*)(ws + 131328);       // 32 f32, then total (contiguous)
    float* total  = (float*)(ws + 131456);       // 1 f32
    float* h1ab   = (float*)(ws + 131584);       // 2048 f32
    float* h2ab   = (float*)(ws + 139776);       // 2048 f32
    unsigned short* wfT = (unsigned short*)(ws + 262144);  // 32*16384 bf16 = 1 MB

    k_zero       <<<1,    33,   0, stream>>>(gc);
    k_attn_scores<<<N_NODES/8, 256, 0, stream>>>(x, aw1, ab1, aw2, ab2, aw3, ab3, scores);
    k_softmax_red<<<1,    1024, 0, stream>>>(scores, red);
    k_attn_wf    <<<N_NODES/256, 256, 0, stream>>>(scores, red, x, attn, wfT, gc);
    k_context    <<<2048, 256,  0, stream>>>(A, wfT, x, attn, total);
    k_mlp1       <<<1,    1024, 0, stream>>>(gc, total, gw1, gb1, h1ab);
    k_mlp2       <<<128,  256,  0, stream>>>(h1ab, gw2, gb2, h2ab);
    k_mlp3       <<<16,   512,  0, stream>>>(h2ab, gw3, gb3, out);
}

// Round 6
// 363.769 us; speedup vs baseline: 1.5459x; 1.0124x over previous
//
#include <hip/hip_runtime.h>
#include <hip/hip_bf16.h>
#include <math.h>

#define N_NODES 16384
#define C_IN 32
#define BK 256            // k_context tile width (cols per stage)

typedef __attribute__((ext_vector_type(8))) short short8;
typedef __attribute__((ext_vector_type(4))) short s16x4;
typedef __attribute__((ext_vector_type(4))) float f32x4;
typedef __attribute__((ext_vector_type(4))) float f4v;

__device__ __forceinline__ unsigned short f2bf(float f) {
    unsigned u = __float_as_uint(f);
    u = u + 0x7fffu + ((u >> 16) & 1u);   // RNE to bf16
    return (unsigned short)(u >> 16);
}

// ---------------------------------------------------------------------------
// K0: zero gc[32] + total[1] (contiguous 33 floats)
// ---------------------------------------------------------------------------
__global__ void k_zero(float* __restrict__ p) {
    p[threadIdx.x] = 0.f;
}

// ---------------------------------------------------------------------------
// K1: attention scores.  8 nodes per 256-thread block.
// ---------------------------------------------------------------------------
__global__ __launch_bounds__(256) void k_attn_scores(
    const float* __restrict__ x,
    const float* __restrict__ aw1, const float* __restrict__ ab1,
    const float* __restrict__ aw2, const float* __restrict__ ab2,
    const float* __restrict__ aw3, const float* __restrict__ ab3,
    float* __restrict__ scores)
{
    __shared__ float w1s[4096];   // [32][128]
    __shared__ float w2s[8192];   // [128][64]
    __shared__ float b1s[128];
    __shared__ float b2s[64];
    __shared__ float w3s[64];
    __shared__ float xs[256];     // 8 nodes x 32 ch
    __shared__ float h1s[1024];   // 8 nodes x 128

    const int tid = threadIdx.x;
    for (int i = tid; i < 4096; i += 256) w1s[i] = aw1[i];
    for (int i = tid; i < 8192; i += 256) w2s[i] = aw2[i];
    if (tid < 128) b1s[tid] = ab1[tid];
    if (tid < 64)  { b2s[tid] = ab2[tid]; w3s[tid] = aw3[tid]; }
    xs[tid] = x[(size_t)blockIdx.x * 256 + tid];
    __syncthreads();

    const int nl  = tid >> 5;   // node 0..7
    const int t31 = tid & 31;

    // layer 1: outputs o = t31*4 + {0..3}
    float a0 = b1s[t31*4+0], a1 = b1s[t31*4+1], a2 = b1s[t31*4+2], a3 = b1s[t31*4+3];
    #pragma unroll
    for (int c = 0; c < 32; ++c) {
        float xv = xs[nl*32 + c];
        float4 w = *(const float4*)&w1s[c*128 + t31*4];
        a0 += xv * w.x; a1 += xv * w.y; a2 += xv * w.z; a3 += xv * w.w;
    }
    *(float4*)&h1s[nl*128 + t31*4] =
        make_float4(fmaxf(a0,0.f), fmaxf(a1,0.f), fmaxf(a2,0.f), fmaxf(a3,0.f));
    __syncthreads();

    // layer 2 + dot with w3: outputs o = t31*2 + {0,1}
    float c0 = b2s[t31*2], c1 = b2s[t31*2 + 1];
    #pragma unroll 8
    for (int o = 0; o < 128; ++o) {
        float hv = h1s[nl*128 + o];
        float2 w = *(const float2*)&w2s[o*64 + t31*2];
        c0 += hv * w.x;
        c1 += hv * w.y;
    }
    float s = fmaxf(c0, 0.f) * w3s[t31*2] + fmaxf(c1, 0.f) * w3s[t31*2 + 1];
    s += __shfl_xor(s, 1);  s += __shfl_xor(s, 2);  s += __shfl_xor(s, 4);
    s += __shfl_xor(s, 8);  s += __shfl_xor(s, 16);
    if (t31 == 0) scores[(size_t)blockIdx.x * 8 + nl] = s + ab3[0];
}

// ---------------------------------------------------------------------------
// K2: softmax max + sum(exp) over 16384 scores, single block
// ---------------------------------------------------------------------------
__global__ __launch_bounds__(1024) void k_softmax_red(
    const float* __restrict__ scores, float* __restrict__ red)
{
    __shared__ float sm[1024];
    const int tid = threadIdx.x;
    float m = -3.4e38f;
    for (int i = tid; i < N_NODES; i += 1024) m = fmaxf(m, scores[i]);
    sm[tid] = m; __syncthreads();
    for (int s = 512; s > 0; s >>= 1) {
        if (tid < s) sm[tid] = fmaxf(sm[tid], sm[tid + s]);
        __syncthreads();
    }
    m = sm[0];
    __syncthreads();
    float acc = 0.f;
    for (int i = tid; i < N_NODES; i += 1024) acc += expf(scores[i] - m);
    sm[tid] = acc; __syncthreads();
    for (int s = 512; s > 0; s >>= 1) {
        if (tid < s) sm[tid] += sm[tid + s];
        __syncthreads();
    }
    if (tid == 0) { red[0] = m; red[1] = sm[0]; }
}

// ---------------------------------------------------------------------------
// K3: attn = softmax(scores); wfT(bf16, transposed [32][16384]); gc = sum(wf)
// ---------------------------------------------------------------------------
__global__ __launch_bounds__(256) void k_attn_wf(
    const float* __restrict__ scores, const float* __restrict__ red,
    const float* __restrict__ x, float* __restrict__ attn,
    unsigned short* __restrict__ wfT, float* __restrict__ gc)
{
    const int n = blockIdx.x * 256 + threadIdx.x;
    const float m = red[0], s = red[1];
    const float a = expf(scores[n] - m) / s;
    attn[n] = a;

    float wv[32];
    const float4* xr = (const float4*)(x + (size_t)n * 32);
    #pragma unroll
    for (int q = 0; q < 8; ++q) {
        float4 v = xr[q];
        wv[q*4+0] = v.x * a; wv[q*4+1] = v.y * a;
        wv[q*4+2] = v.z * a; wv[q*4+3] = v.w * a;
    }
    #pragma unroll
    for (int c = 0; c < 32; ++c)
        wfT[(size_t)c * N_NODES + n] = f2bf(wv[c]);   // coalesced per c

    const int lane = threadIdx.x & 63;
    #pragma unroll
    for (int c = 0; c < 32; ++c) {
        float v = wv[c];
        v += __shfl_xor(v, 1);  v += __shfl_xor(v, 2);  v += __shfl_xor(v, 4);
        v += __shfl_xor(v, 8);  v += __shfl_xor(v, 16); v += __shfl_xor(v, 32);
        if (lane == 0) atomicAdd(&gc[c], v);
    }
}

// ---------------------------------------------------------------------------
// K5: total = sum_i dot(AW[i,:], wf[i,:]), AW = A @ WF, bf16 MFMA.
//     v3: fixes the in-order-vmcnt serialization of v2. Per tile:
//       (1) B fragments for CURRENT tile -> registers (L1/L2-fast, issued
//           FIRST so nothing waits behind the HBM stream),
//       (2) A staging loads for NEXT tile (HBM, issued after B),
//       (3) kk-loop: ds_read A-frag + MFMA with reg-B only -> waits
//           vmcnt(16) (A still outstanding) instead of vmcnt(~0),
//       (4) cvt+ds_write next tile (the only vmcnt(0), = the BW drain).
//     FP order identical to v2 -> bitwise-same result.
// ---------------------------------------------------------------------------
__global__ __launch_bounds__(256, 2) void k_context(
    const float* __restrict__ A, const unsigned short* __restrict__ wfT,
    const float* __restrict__ x, const float* __restrict__ attn,
    float* __restrict__ total)
{
    __shared__ unsigned short sA[2][64 * BK];   // 32KB each buffer

    const int tid  = threadIdx.x;
    const int wid  = tid >> 6, lane = tid & 63;
    const int rb   = blockIdx.x & 255;   // 256 row-blocks of 64 rows
    const int js   = blockIdx.x >> 8;    // 8 K-splits of 2048 cols
    const int i0   = rb * 64 + wid * 16; // wave's first A row (stages its own rows)
    const int col0 = js * 2048;

    const int q    = lane >> 4;          // quadrant 0..3
    const int r16  = lane & 15;
    const int lr   = wid * 16 + r16;     // local row for MFMA A-frag
    const int swzR = (r16 & 7) << 4;     // read-side swizzle key (row&7)

    const unsigned short* bp0 = wfT + (size_t)r16 * N_NODES;
    const unsigned short* bp1 = bp0 + (size_t)16 * N_NODES;

    f32x4 acc0 = {0.f, 0.f, 0.f, 0.f};
    f32x4 acc1 = {0.f, 0.f, 0.f, 0.f};

    // ---- prologue: stage tile 0 into buffer 0 ----
    {
        #pragma unroll
        for (int r = 0; r < 16; ++r) {
            f4v v = __builtin_nontemporal_load(
                (const f4v*)(A + (size_t)(i0 + r) * N_NODES + col0 + lane * 4));
            s16x4 w;
            w[0] = (short)f2bf(v[0]); w[1] = (short)f2bf(v[1]);
            w[2] = (short)f2bf(v[2]); w[3] = (short)f2bf(v[3]);
            int off = (wid*16 + r) * (BK*2) + ((lane*8) ^ ((r & 7) << 4));
            *(s16x4*)((char*)sA[0] + off) = w;
        }
    }
    __syncthreads();

    // ---- main loop: 8 tiles of 256 cols ----
    for (int t = 0; t < 8; ++t) {
        const int cur  = t & 1;
        const int tcol = col0 + t * BK;

        // (1) B fragments for CURRENT tile -> regs (issued before the A stream)
        short8 br0[8], br1[8];
        #pragma unroll
        for (int kk = 0; kk < 8; ++kk) {
            br0[kk] = *(const short8*)(bp0 + tcol + kk*32 + q*8);
            br1[kk] = *(const short8*)(bp1 + tcol + kk*32 + q*8);
        }

        // (2) A staging loads for NEXT tile (HBM; stay in flight through compute)
        f4v ldv[16];
        if (t < 7) {
            const int cnext = col0 + (t + 1) * BK + lane * 4;
            #pragma unroll
            for (int r = 0; r < 16; ++r)
                ldv[r] = __builtin_nontemporal_load(
                    (const f4v*)(A + (size_t)(i0 + r) * N_NODES + cnext));
        }

        // (3) compute current tile: LDS A-frags + reg B only
        const char* base = (const char*)sA[cur];
        #pragma unroll
        for (int kk = 0; kk < 8; ++kk) {
            int off = lr * (BK*2) + ((kk*64 + q*16) ^ swzR);
            short8 av = *(const short8*)(base + off);
            acc0 = __builtin_amdgcn_mfma_f32_16x16x32_bf16(av, br0[kk], acc0, 0, 0, 0);
            acc1 = __builtin_amdgcn_mfma_f32_16x16x32_bf16(av, br1[kk], acc1, 0, 0, 0);
        }

        // (4) convert + write next tile into the other buffer (vmcnt(0) here)
        if (t < 7) {
            #pragma unroll
            for (int r = 0; r < 16; ++r) {
                s16x4 w;
                w[0] = (short)f2bf(ldv[r][0]); w[1] = (short)f2bf(ldv[r][1]);
                w[2] = (short)f2bf(ldv[r][2]); w[3] = (short)f2bf(ldv[r][3]);
                int off = (wid*16 + r) * (BK*2) + ((lane*8) ^ ((r & 7) << 4));
                *(s16x4*)((char*)sA[cur ^ 1] + off) = w;
            }
        }
        __syncthreads();
    }

    // ---- epilogue: D[row=(lane>>4)*4+r, col=lane&15]; dot with wf, reduce ----
    float partial = 0.f;
    #pragma unroll
    for (int r = 0; r < 4; ++r) {
        const int i = i0 + q * 4 + r;
        const float a = attn[i];
        partial += acc0[r] * (x[(size_t)i * 32 + r16]      * a);
        partial += acc1[r] * (x[(size_t)i * 32 + 16 + r16] * a);
    }
    partial += __shfl_xor(partial, 1);  partial += __shfl_xor(partial, 2);
    partial += __shfl_xor(partial, 4);  partial += __shfl_xor(partial, 8);
    partial += __shfl_xor(partial, 16); partial += __shfl_xor(partial, 32);
    if (lane == 0) atomicAdd(total, partial);
}

// ---------------------------------------------------------------------------
// K6a: h1 for both gc and gc2 = gc + 0.001*(total/N)
// ---------------------------------------------------------------------------
__global__ __launch_bounds__(1024) void k_mlp1(
    const float* __restrict__ gc, const float* __restrict__ total,
    const float* __restrict__ w1, const float* __restrict__ b1,
    float* __restrict__ h1ab)
{
    __shared__ float g1[32], g2[32];
    const int t = threadIdx.x;
    if (t < 32) {
        float cs = total[0] * (1.0f / 16384.0f);
        g1[t] = gc[t];
        g2[t] = gc[t] + 0.001f * cs;
    }
    __syncthreads();
    float s1 = b1[t], s2 = b1[t];
    #pragma unroll
    for (int c = 0; c < 32; ++c) {
        float wv = w1[(size_t)c * 1024 + t];
        s1 += g1[c] * wv;
        s2 += g2[c] * wv;
    }
    h1ab[t]        = fmaxf(s1, 0.f);
    h1ab[1024 + t] = fmaxf(s2, 0.f);
}

// ---------------------------------------------------------------------------
// K6b: h2 = relu(h1 @ w2 + b2), split-K (16 K-groups of 64), LDS tree reduce.
// ---------------------------------------------------------------------------
__global__ __launch_bounds__(256) void k_mlp2(
    const float* __restrict__ h1ab, const float* __restrict__ w2,
    const float* __restrict__ b2, float* __restrict__ h2ab)
{
    __shared__ float h1s[1024];
    __shared__ float sm[256];
    const int v   = blockIdx.x & 1;
    const int ob  = blockIdx.x >> 1;      // 0..63
    const int tid = threadIdx.x;
    const int o   = tid & 15, g = tid >> 4;
    for (int i = tid; i < 1024; i += 256) h1s[i] = h1ab[v * 1024 + i];
    __syncthreads();
    const float* wp = w2 + (size_t)(g * 64) * 1024 + ob * 16 + o;
    float acc = 0.f;
    #pragma unroll 8
    for (int k = 0; k < 64; ++k)
        acc += h1s[g * 64 + k] * wp[(size_t)k * 1024];
    sm[tid] = acc;
    __syncthreads();
    if (tid < 16) {
        float s = b2[ob * 16 + tid];
        #pragma unroll
        for (int g2 = 0; g2 < 16; ++g2) s += sm[g2 * 16 + tid];
        h2ab[v * 1024 + ob * 16 + tid] = fmaxf(s, 0.f);
    }
}

// ---------------------------------------------------------------------------
// K6c: out = relu(h2a@w3+b3) + 0.002*relu(h2b@w3+b3), split-K, both variants.
// ---------------------------------------------------------------------------
__global__ __launch_bounds__(512) void k_mlp3(
    const float* __restrict__ h2ab, const float* __restrict__ w3,
    const float* __restrict__ b3, float* __restrict__ out)
{
    __shared__ float sm[512];
    const int tid = threadIdx.x;
    const int v   = tid >> 8;
    const int g   = (tid >> 4) & 15;
    const int o   = tid & 15;
    const int ob  = blockIdx.x;           // 16 blocks x 16 outputs
    const float* hp = h2ab + v * 1024 + g * 64;
    const float* wp = w3 + (size_t)(g * 64) * 256 + ob * 16 + o;
    float acc = 0.f;
    #pragma unroll 8
    for (int k = 0; k < 64; ++k)
        acc += hp[k] * wp[(size_t)k * 256];
    sm[tid] = acc;
    __syncthreads();
    if (tid < 16) {
        float pa = b3[ob * 16 + tid], pb = pa;
        #pragma unroll
        for (int g2 = 0; g2 < 16; ++g2) {
            pa += sm[g2 * 16 + tid];
            pb += sm[256 + g2 * 16 + tid];
        }
        out[ob * 16 + tid] = fmaxf(pa, 0.f) + 0.002f * fmaxf(pb, 0.f);
    }
}

// ---------------------------------------------------------------------------
extern "C" void kernel_launch(void* const* d_in, const int* in_sizes, int n_in,
                              void* d_out, int out_size, void* d_ws, size_t ws_size,
                              hipStream_t stream)
{
    const float* x   = (const float*)d_in[0];
    const float* A   = (const float*)d_in[1];
    const float* gw1 = (const float*)d_in[2];
    const float* gb1 = (const float*)d_in[3];
    const float* gw2 = (const float*)d_in[4];
    const float* gb2 = (const float*)d_in[5];
    const float* gw3 = (const float*)d_in[6];
    const float* gb3 = (const float*)d_in[7];
    const float* aw1 = (const float*)d_in[8];
    const float* ab1 = (const float*)d_in[9];
    const float* aw2 = (const float*)d_in[10];
    const float* ab2 = (const float*)d_in[11];
    const float* aw3 = (const float*)d_in[12];
    const float* ab3 = (const float*)d_in[13];
    float* out = (float*)d_out;

    char* ws = (char*)d_ws;
    float* scores = (float*)(ws + 0);            // 16384 f32
    float* attn   = (float*)(ws + 65536);        // 16384 f32
    float* red    = (float*)(ws + 131072);       // 2 f32 (max, sumexp)
    float* gc     = (float*)(ws + 131328);       // 32 f32, then total (contiguous)
    float* total  = (float*)(ws + 131456);       // 1 f32
    float* h1ab   = (float*)(ws + 131584);       // 2048 f32
    float* h2ab   = (float*)(ws + 139776);       // 2048 f32
    unsigned short* wfT = (unsigned short*)(ws + 262144);  // 32*16384 bf16 = 1 MB

    k_zero       <<<1,    33,   0, stream>>>(gc);
    k_attn_scores<<<N_NODES/8, 256, 0, stream>>>(x, aw1, ab1, aw2, ab2, aw3, ab3, scores);
    k_softmax_red<<<1,    1024, 0, stream>>>(scores, red);
    k_attn_wf    <<<N_NODES/256, 256, 0, stream>>>(scores, red, x, attn, wfT, gc);
    k_context    <<<2048, 256,  0, stream>>>(A, wfT, x, attn, total);
    k_mlp1       <<<1,    1024, 0, stream>>>(gc, total, gw1, gb1, h1ab);
    k_mlp2       <<<128,  256,  0, stream>>>(h1ab, gw2, gb2, h2ab);
    k_mlp3       <<<16,   512,  0, stream>>>(h2ab, gw3, gb3, out);
}

// Round 7
// 358.483 us; speedup vs baseline: 1.5687x; 1.0147x over previous
//
#include <hip/hip_runtime.h>
#include <hip/hip_bf16.h>
#include <math.h>

#define N_NODES 16384
#define C_IN 32
#define BK 128            // k_context tile width (cols per step)
#define NT 16             // 2048 / BK steps per block

typedef __attribute__((ext_vector_type(8))) short short8;
typedef __attribute__((ext_vector_type(4))) short s16x4;
typedef __attribute__((ext_vector_type(4))) float f32x4;
typedef __attribute__((ext_vector_type(4))) float f4v;

__device__ __forceinline__ unsigned short f2bf(float f) {
    unsigned u = __float_as_uint(f);
    u = u + 0x7fffu + ((u >> 16) & 1u);   // RNE to bf16
    return (unsigned short)(u >> 16);
}

// ---------------------------------------------------------------------------
// K0: zero gc[32] + total[1] (contiguous 33 floats)
// ---------------------------------------------------------------------------
__global__ void k_zero(float* __restrict__ p) {
    p[threadIdx.x] = 0.f;
}

// ---------------------------------------------------------------------------
// K1: attention scores.  8 nodes per 256-thread block.
// ---------------------------------------------------------------------------
__global__ __launch_bounds__(256) void k_attn_scores(
    const float* __restrict__ x,
    const float* __restrict__ aw1, const float* __restrict__ ab1,
    const float* __restrict__ aw2, const float* __restrict__ ab2,
    const float* __restrict__ aw3, const float* __restrict__ ab3,
    float* __restrict__ scores)
{
    __shared__ float w1s[4096];   // [32][128]
    __shared__ float w2s[8192];   // [128][64]
    __shared__ float b1s[128];
    __shared__ float b2s[64];
    __shared__ float w3s[64];
    __shared__ float xs[256];     // 8 nodes x 32 ch
    __shared__ float h1s[1024];   // 8 nodes x 128

    const int tid = threadIdx.x;
    for (int i = tid; i < 4096; i += 256) w1s[i] = aw1[i];
    for (int i = tid; i < 8192; i += 256) w2s[i] = aw2[i];
    if (tid < 128) b1s[tid] = ab1[tid];
    if (tid < 64)  { b2s[tid] = ab2[tid]; w3s[tid] = aw3[tid]; }
    xs[tid] = x[(size_t)blockIdx.x * 256 + tid];
    __syncthreads();

    const int nl  = tid >> 5;   // node 0..7
    const int t31 = tid & 31;

    // layer 1: outputs o = t31*4 + {0..3}
    float a0 = b1s[t31*4+0], a1 = b1s[t31*4+1], a2 = b1s[t31*4+2], a3 = b1s[t31*4+3];
    #pragma unroll
    for (int c = 0; c < 32; ++c) {
        float xv = xs[nl*32 + c];
        float4 w = *(const float4*)&w1s[c*128 + t31*4];
        a0 += xv * w.x; a1 += xv * w.y; a2 += xv * w.z; a3 += xv * w.w;
    }
    *(float4*)&h1s[nl*128 + t31*4] =
        make_float4(fmaxf(a0,0.f), fmaxf(a1,0.f), fmaxf(a2,0.f), fmaxf(a3,0.f));
    __syncthreads();

    // layer 2 + dot with w3: outputs o = t31*2 + {0,1}
    float c0 = b2s[t31*2], c1 = b2s[t31*2 + 1];
    #pragma unroll 8
    for (int o = 0; o < 128; ++o) {
        float hv = h1s[nl*128 + o];
        float2 w = *(const float2*)&w2s[o*64 + t31*2];
        c0 += hv * w.x;
        c1 += hv * w.y;
    }
    float s = fmaxf(c0, 0.f) * w3s[t31*2] + fmaxf(c1, 0.f) * w3s[t31*2 + 1];
    s += __shfl_xor(s, 1);  s += __shfl_xor(s, 2);  s += __shfl_xor(s, 4);
    s += __shfl_xor(s, 8);  s += __shfl_xor(s, 16);
    if (t31 == 0) scores[(size_t)blockIdx.x * 8 + nl] = s + ab3[0];
}

// ---------------------------------------------------------------------------
// K2: softmax max + sum(exp) over 16384 scores, single block
// ---------------------------------------------------------------------------
__global__ __launch_bounds__(1024) void k_softmax_red(
    const float* __restrict__ scores, float* __restrict__ red)
{
    __shared__ float sm[1024];
    const int tid = threadIdx.x;
    float m = -3.4e38f;
    for (int i = tid; i < N_NODES; i += 1024) m = fmaxf(m, scores[i]);
    sm[tid] = m; __syncthreads();
    for (int s = 512; s > 0; s >>= 1) {
        if (tid < s) sm[tid] = fmaxf(sm[tid], sm[tid + s]);
        __syncthreads();
    }
    m = sm[0];
    __syncthreads();
    float acc = 0.f;
    for (int i = tid; i < N_NODES; i += 1024) acc += expf(scores[i] - m);
    sm[tid] = acc; __syncthreads();
    for (int s = 512; s > 0; s >>= 1) {
        if (tid < s) sm[tid] += sm[tid + s];
        __syncthreads();
    }
    if (tid == 0) { red[0] = m; red[1] = sm[0]; }
}

// ---------------------------------------------------------------------------
// K3: attn = softmax(scores); wfT(bf16, transposed [32][16384]); gc = sum(wf)
// ---------------------------------------------------------------------------
__global__ __launch_bounds__(256) void k_attn_wf(
    const float* __restrict__ scores, const float* __restrict__ red,
    const float* __restrict__ x, float* __restrict__ attn,
    unsigned short* __restrict__ wfT, float* __restrict__ gc)
{
    const int n = blockIdx.x * 256 + threadIdx.x;
    const float m = red[0], s = red[1];
    const float a = expf(scores[n] - m) / s;
    attn[n] = a;

    float wv[32];
    const float4* xr = (const float4*)(x + (size_t)n * 32);
    #pragma unroll
    for (int q = 0; q < 8; ++q) {
        float4 v = xr[q];
        wv[q*4+0] = v.x * a; wv[q*4+1] = v.y * a;
        wv[q*4+2] = v.z * a; wv[q*4+3] = v.w * a;
    }
    #pragma unroll
    for (int c = 0; c < 32; ++c)
        wfT[(size_t)c * N_NODES + n] = f2bf(wv[c]);   // coalesced per c

    const int lane = threadIdx.x & 63;
    #pragma unroll
    for (int c = 0; c < 32; ++c) {
        float v = wv[c];
        v += __shfl_xor(v, 1);  v += __shfl_xor(v, 2);  v += __shfl_xor(v, 4);
        v += __shfl_xor(v, 8);  v += __shfl_xor(v, 16); v += __shfl_xor(v, 32);
        if (lane == 0) atomicAdd(&gc[c], v);
    }
}

// ---------------------------------------------------------------------------
// K5 step: one BK=128 tile. B batch FIRST (so in-order vmcnt retire never
// waits on the deep A prefetch), then issue A(T+3), then MFMA from the
// wave-private LDS buffer, then cvt+write A(T+1) into the other buffer.
// No __syncthreads anywhere: LDS regions are wave-private (each wave stages
// and consumes only its own 16 rows) -> waves free-run, pipe never drains.
// ---------------------------------------------------------------------------
template<int T>
__device__ __forceinline__ void ctx_step(
    const float* __restrict__ A,
    const unsigned short* __restrict__ bp0, const unsigned short* __restrict__ bp1,
    char* wbase, int i0, int col0, int l2r, int c4, int q, int r16,
    int swzR, int wrByte, f4v (&riss)[8], f4v (&rwr)[8],
    f32x4& acc0, f32x4& acc1)
{
    const int tcol = col0 + T * BK;
    // (1) B fragments for tile T (L1/L2-resident wfT), issued before A
    short8 b0r[4], b1r[4];
    #pragma unroll
    for (int kk = 0; kk < 4; ++kk) {
        b0r[kk] = *(const short8*)(bp0 + tcol + kk*32 + q*8);
        b1r[kk] = *(const short8*)(bp1 + tcol + kk*32 + q*8);
    }
    // (2) deep prefetch: A(T+3) -> riss (stays in flight for 3 steps)
    if constexpr (T + 3 < NT) {
        const int cn = col0 + (T + 3) * BK + c4;
        #pragma unroll
        for (int r = 0; r < 8; ++r)
            riss[r] = __builtin_nontemporal_load(
                (const f4v*)(A + (size_t)(i0 + 2*r + l2r) * N_NODES + cn));
    }
    // (3) compute tile T from wave-private LDS buffer (T&1)
    const char* bb = wbase + (T & 1) * 4096;
    #pragma unroll
    for (int kk = 0; kk < 4; ++kk) {
        short8 av = *(const short8*)(bb + r16*256 + ((kk*64 + q*16) ^ swzR));
        acc0 = __builtin_amdgcn_mfma_f32_16x16x32_bf16(av, b0r[kk], acc0, 0, 0, 0);
        acc1 = __builtin_amdgcn_mfma_f32_16x16x32_bf16(av, b1r[kk], acc1, 0, 0, 0);
    }
    // (4) cvt + write A(T+1) (retired already: it is older than B(T)) -> buffer (T+1)&1
    if constexpr (T + 1 < NT) {
        char* wb = wbase + ((T + 1) & 1) * 4096;
        #pragma unroll
        for (int r = 0; r < 8; ++r) {
            const int row = 2*r + l2r;
            s16x4 w;
            w[0] = (short)f2bf(rwr[r][0]); w[1] = (short)f2bf(rwr[r][1]);
            w[2] = (short)f2bf(rwr[r][2]); w[3] = (short)f2bf(rwr[r][3]);
            *(s16x4*)(wb + row*256 + (wrByte ^ ((row & 7) << 4))) = w;
        }
    }
    __builtin_amdgcn_sched_barrier(0);   // pin tile boundaries (coarse only)
}

__global__ __launch_bounds__(256, 2) void k_context(
    const float* __restrict__ A, const unsigned short* __restrict__ wfT,
    const float* __restrict__ x, const float* __restrict__ attn,
    float* __restrict__ total)
{
    __shared__ short sA[4][2][2048];     // per-wave private: [wid][buf][16 rows x 128 cols]

    const int tid  = threadIdx.x;
    const int wid  = tid >> 6, lane = tid & 63;
    const int rb   = blockIdx.x & 255;   // 256 row-blocks of 64 rows
    const int js   = blockIdx.x >> 8;    // 8 K-splits of 2048 cols
    const int i0   = rb * 64 + wid * 16;
    const int col0 = js * 2048;

    const int q    = lane >> 4;          // quadrant 0..3
    const int r16  = lane & 15;
    const int swzR = (r16 & 7) << 4;
    const int l2r  = lane >> 5;          // 0/1: which of 2 rows this lane stages
    const int c4   = (lane & 31) * 4;    // staged col (fp32 elems)
    const int wrByte = (lane & 31) * 8;  // staged LDS byte (bf16)

    char* wbase = (char*)sA[wid];
    const unsigned short* bp0 = wfT + (size_t)r16 * N_NODES;
    const unsigned short* bp1 = bp0 + (size_t)16 * N_NODES;

    f32x4 acc0 = {0.f, 0.f, 0.f, 0.f};
    f32x4 acc1 = {0.f, 0.f, 0.f, 0.f};

    f4v s0[8], s1[8], s2[8];

    // ---- prologue: issue A(0),A(1),A(2); write A(0) -> buf0 ----
    #pragma unroll
    for (int r = 0; r < 8; ++r)
        s0[r] = __builtin_nontemporal_load(
            (const f4v*)(A + (size_t)(i0 + 2*r + l2r) * N_NODES + col0 + c4));
    #pragma unroll
    for (int r = 0; r < 8; ++r)
        s1[r] = __builtin_nontemporal_load(
            (const f4v*)(A + (size_t)(i0 + 2*r + l2r) * N_NODES + col0 + BK + c4));
    #pragma unroll
    for (int r = 0; r < 8; ++r)
        s2[r] = __builtin_nontemporal_load(
            (const f4v*)(A + (size_t)(i0 + 2*r + l2r) * N_NODES + col0 + 2*BK + c4));
    #pragma unroll
    for (int r = 0; r < 8; ++r) {
        const int row = 2*r + l2r;
        s16x4 w;
        w[0] = (short)f2bf(s0[r][0]); w[1] = (short)f2bf(s0[r][1]);
        w[2] = (short)f2bf(s0[r][2]); w[3] = (short)f2bf(s0[r][3]);
        *(s16x4*)(wbase + row*256 + (wrByte ^ ((row & 7) << 4))) = w;
    }
    __builtin_amdgcn_sched_barrier(0);

    // ---- 16 steps, 3-deep rotation: riss = s[T%3], rwr = s[(T+1)%3] ----
    ctx_step< 0>(A, bp0, bp1, wbase, i0, col0, l2r, c4, q, r16, swzR, wrByte, s0, s1, acc0, acc1);
    ctx_step< 1>(A, bp0, bp1, wbase, i0, col0, l2r, c4, q, r16, swzR, wrByte, s1, s2, acc0, acc1);
    ctx_step< 2>(A, bp0, bp1, wbase, i0, col0, l2r, c4, q, r16, swzR, wrByte, s2, s0, acc0, acc1);
    ctx_step< 3>(A, bp0, bp1, wbase, i0, col0, l2r, c4, q, r16, swzR, wrByte, s0, s1, acc0, acc1);
    ctx_step< 4>(A, bp0, bp1, wbase, i0, col0, l2r, c4, q, r16, swzR, wrByte, s1, s2, acc0, acc1);
    ctx_step< 5>(A, bp0, bp1, wbase, i0, col0, l2r, c4, q, r16, swzR, wrByte, s2, s0, acc0, acc1);
    ctx_step< 6>(A, bp0, bp1, wbase, i0, col0, l2r, c4, q, r16, swzR, wrByte, s0, s1, acc0, acc1);
    ctx_step< 7>(A, bp0, bp1, wbase, i0, col0, l2r, c4, q, r16, swzR, wrByte, s1, s2, acc0, acc1);
    ctx_step< 8>(A, bp0, bp1, wbase, i0, col0, l2r, c4, q, r16, swzR, wrByte, s2, s0, acc0, acc1);
    ctx_step< 9>(A, bp0, bp1, wbase, i0, col0, l2r, c4, q, r16, swzR, wrByte, s0, s1, acc0, acc1);
    ctx_step<10>(A, bp0, bp1, wbase, i0, col0, l2r, c4, q, r16, swzR, wrByte, s1, s2, acc0, acc1);
    ctx_step<11>(A, bp0, bp1, wbase, i0, col0, l2r, c4, q, r16, swzR, wrByte, s2, s0, acc0, acc1);
    ctx_step<12>(A, bp0, bp1, wbase, i0, col0, l2r, c4, q, r16, swzR, wrByte, s0, s1, acc0, acc1);
    ctx_step<13>(A, bp0, bp1, wbase, i0, col0, l2r, c4, q, r16, swzR, wrByte, s1, s2, acc0, acc1);
    ctx_step<14>(A, bp0, bp1, wbase, i0, col0, l2r, c4, q, r16, swzR, wrByte, s2, s0, acc0, acc1);
    ctx_step<15>(A, bp0, bp1, wbase, i0, col0, l2r, c4, q, r16, swzR, wrByte, s0, s1, acc0, acc1);

    // ---- epilogue: D[row=q*4+r, col=r16]; dot with wf = x*attn, reduce ----
    float partial = 0.f;
    #pragma unroll
    for (int r = 0; r < 4; ++r) {
        const int i = i0 + q * 4 + r;
        const float a = attn[i];
        partial += acc0[r] * (x[(size_t)i * 32 + r16]      * a);
        partial += acc1[r] * (x[(size_t)i * 32 + 16 + r16] * a);
    }
    partial += __shfl_xor(partial, 1);  partial += __shfl_xor(partial, 2);
    partial += __shfl_xor(partial, 4);  partial += __shfl_xor(partial, 8);
    partial += __shfl_xor(partial, 16); partial += __shfl_xor(partial, 32);
    if (lane == 0) atomicAdd(total, partial);
}

// ---------------------------------------------------------------------------
// K6a: h1 for both gc and gc2 = gc + 0.001*(total/N)
// ---------------------------------------------------------------------------
__global__ __launch_bounds__(1024) void k_mlp1(
    const float* __restrict__ gc, const float* __restrict__ total,
    const float* __restrict__ w1, const float* __restrict__ b1,
    float* __restrict__ h1ab)
{
    __shared__ float g1[32], g2[32];
    const int t = threadIdx.x;
    if (t < 32) {
        float cs = total[0] * (1.0f / 16384.0f);
        g1[t] = gc[t];
        g2[t] = gc[t] + 0.001f * cs;
    }
    __syncthreads();
    float s1 = b1[t], s2 = b1[t];
    #pragma unroll
    for (int c = 0; c < 32; ++c) {
        float wv = w1[(size_t)c * 1024 + t];
        s1 += g1[c] * wv;
        s2 += g2[c] * wv;
    }
    h1ab[t]        = fmaxf(s1, 0.f);
    h1ab[1024 + t] = fmaxf(s2, 0.f);
}

// ---------------------------------------------------------------------------
// K6b: h2 = relu(h1 @ w2 + b2), split-K (16 K-groups of 64), LDS tree reduce.
// ---------------------------------------------------------------------------
__global__ __launch_bounds__(256) void k_mlp2(
    const float* __restrict__ h1ab, const float* __restrict__ w2,
    const float* __restrict__ b2, float* __restrict__ h2ab)
{
    __shared__ float h1s[1024];
    __shared__ float sm[256];
    const int v   = blockIdx.x & 1;
    const int ob  = blockIdx.x >> 1;      // 0..63
    const int tid = threadIdx.x;
    const int o   = tid & 15, g = tid >> 4;
    for (int i = tid; i < 1024; i += 256) h1s[i] = h1ab[v * 1024 + i];
    __syncthreads();
    const float* wp = w2 + (size_t)(g * 64) * 1024 + ob * 16 + o;
    float acc = 0.f;
    #pragma unroll 8
    for (int k = 0; k < 64; ++k)
        acc += h1s[g * 64 + k] * wp[(size_t)k * 1024];
    sm[tid] = acc;
    __syncthreads();
    if (tid < 16) {
        float s = b2[ob * 16 + tid];
        #pragma unroll
        for (int g2 = 0; g2 < 16; ++g2) s += sm[g2 * 16 + tid];
        h2ab[v * 1024 + ob * 16 + tid] = fmaxf(s, 0.f);
    }
}

// ---------------------------------------------------------------------------
// K6c: out = relu(h2a@w3+b3) + 0.002*relu(h2b@w3+b3), split-K, both variants.
// ---------------------------------------------------------------------------
__global__ __launch_bounds__(512) void k_mlp3(
    const float* __restrict__ h2ab, const float* __restrict__ w3,
    const float* __restrict__ b3, float* __restrict__ out)
{
    __shared__ float sm[512];
    const int tid = threadIdx.x;
    const int v   = tid >> 8;
    const int g   = (tid >> 4) & 15;
    const int o   = tid & 15;
    const int ob  = blockIdx.x;           // 16 blocks x 16 outputs
    const float* hp = h2ab + v * 1024 + g * 64;
    const float* wp = w3 + (size_t)(g * 64) * 256 + ob * 16 + o;
    float acc = 0.f;
    #pragma unroll 8
    for (int k = 0; k < 64; ++k)
        acc += hp[k] * wp[(size_t)k * 256];
    sm[tid] = acc;
    __syncthreads();
    if (tid < 16) {
        float pa = b3[ob * 16 + tid], pb = pa;
        #pragma unroll
        for (int g2 = 0; g2 < 16; ++g2) {
            pa += sm[g2 * 16 + tid];
            pb += sm[256 + g2 * 16 + tid];
        }
        out[ob * 16 + tid] = fmaxf(pa, 0.f) + 0.002f * fmaxf(pb, 0.f);
    }
}

// ---------------------------------------------------------------------------
extern "C" void kernel_launch(void* const* d_in, const int* in_sizes, int n_in,
                              void* d_out, int out_size, void* d_ws, size_t ws_size,
                              hipStream_t stream)
{
    const float* x   = (const float*)d_in[0];
    const float* A   = (const float*)d_in[1];
    const float* gw1 = (const float*)d_in[2];
    const float* gb1 = (const float*)d_in[3];
    const float* gw2 = (const float*)d_in[4];
    const float* gb2 = (const float*)d_in[5];
    const float* gw3 = (const float*)d_in[6];
    const float* gb3 = (const float*)d_in[7];
    const float* aw1 = (const float*)d_in[8];
    const float* ab1 = (const float*)d_in[9];
    const float* aw2 = (const float*)d_in[10];
    const float* ab2 = (const float*)d_in[11];
    const float* aw3 = (const float*)d_in[12];
    const float* ab3 = (const float*)d_in[13];
    float* out = (float*)d_out;

    char* ws = (char*)d_ws;
    float* scores = (float*)(ws + 0);            // 16384 f32
    float* attn   = (float*)(ws + 65536);        // 16384 f32
    float* red    = (float*)(ws + 131072);       // 2 f32 (max, sumexp)
    float* gc     = (float*)(ws + 131328);       // 32 f32, then total (contiguous)
    float* total  = (float*)(ws + 131456);       // 1 f32
    float* h1ab   = (float*)(ws + 131584);       // 2048 f32
    float* h2ab   = (float*)(ws + 139776);       // 2048 f32
    unsigned short* wfT = (unsigned short*)(ws + 262144);  // 32*16384 bf16 = 1 MB

    k_zero       <<<1,    33,   0, stream>>>(gc);
    k_attn_scores<<<N_NODES/8, 256, 0, stream>>>(x, aw1, ab1, aw2, ab2, aw3, ab3, scores);
    k_softmax_red<<<1,    1024, 0, stream>>>(scores, red);
    k_attn_wf    <<<N_NODES/256, 256, 0, stream>>>(scores, red, x, attn, wfT, gc);
    k_context    <<<2048, 256,  0, stream>>>(A, wfT, x, attn, total);
    k_mlp1       <<<1,    1024, 0, stream>>>(gc, total, gw1, gb1, h1ab);
    k_mlp2       <<<128,  256,  0, stream>>>(h1ab, gw2, gb2, h2ab);
    k_mlp3       <<<16,   512,  0, stream>>>(h2ab, gw3, gb3, out);
}

// Round 8
// 304.873 us; speedup vs baseline: 1.8446x; 1.1758x over previous
//
#include <hip/hip_runtime.h>
#include <hip/hip_bf16.h>
#include <math.h>

#define N_NODES 16384
#define C_IN 32

typedef __attribute__((ext_vector_type(8))) short short8;
typedef __attribute__((ext_vector_type(4))) short s16x4;
typedef __attribute__((ext_vector_type(4))) float f32x4;
typedef __attribute__((ext_vector_type(4))) float f4v;

__device__ __forceinline__ unsigned short f2bf(float f) {
    unsigned u = __float_as_uint(f);
    u = u + 0x7fffu + ((u >> 16) & 1u);   // RNE to bf16
    return (unsigned short)(u >> 16);
}

// ---------------------------------------------------------------------------
// K0: zero gc[32]
// ---------------------------------------------------------------------------
__global__ void k_zero(float* __restrict__ p) {
    p[threadIdx.x] = 0.f;
}

// ---------------------------------------------------------------------------
// K1: attention scores.  8 nodes per 256-thread block.
// ---------------------------------------------------------------------------
__global__ __launch_bounds__(256) void k_attn_scores(
    const float* __restrict__ x,
    const float* __restrict__ aw1, const float* __restrict__ ab1,
    const float* __restrict__ aw2, const float* __restrict__ ab2,
    const float* __restrict__ aw3, const float* __restrict__ ab3,
    float* __restrict__ scores)
{
    __shared__ float w1s[4096];   // [32][128]
    __shared__ float w2s[8192];   // [128][64]
    __shared__ float b1s[128];
    __shared__ float b2s[64];
    __shared__ float w3s[64];
    __shared__ float xs[256];     // 8 nodes x 32 ch
    __shared__ float h1s[1024];   // 8 nodes x 128

    const int tid = threadIdx.x;
    for (int i = tid; i < 4096; i += 256) w1s[i] = aw1[i];
    for (int i = tid; i < 8192; i += 256) w2s[i] = aw2[i];
    if (tid < 128) b1s[tid] = ab1[tid];
    if (tid < 64)  { b2s[tid] = ab2[tid]; w3s[tid] = aw3[tid]; }
    xs[tid] = x[(size_t)blockIdx.x * 256 + tid];
    __syncthreads();

    const int nl  = tid >> 5;   // node 0..7
    const int t31 = tid & 31;

    float a0 = b1s[t31*4+0], a1 = b1s[t31*4+1], a2 = b1s[t31*4+2], a3 = b1s[t31*4+3];
    #pragma unroll
    for (int c = 0; c < 32; ++c) {
        float xv = xs[nl*32 + c];
        float4 w = *(const float4*)&w1s[c*128 + t31*4];
        a0 += xv * w.x; a1 += xv * w.y; a2 += xv * w.z; a3 += xv * w.w;
    }
    *(float4*)&h1s[nl*128 + t31*4] =
        make_float4(fmaxf(a0,0.f), fmaxf(a1,0.f), fmaxf(a2,0.f), fmaxf(a3,0.f));
    __syncthreads();

    float c0 = b2s[t31*2], c1 = b2s[t31*2 + 1];
    #pragma unroll 8
    for (int o = 0; o < 128; ++o) {
        float hv = h1s[nl*128 + o];
        float2 w = *(const float2*)&w2s[o*64 + t31*2];
        c0 += hv * w.x;
        c1 += hv * w.y;
    }
    float s = fmaxf(c0, 0.f) * w3s[t31*2] + fmaxf(c1, 0.f) * w3s[t31*2 + 1];
    s += __shfl_xor(s, 1);  s += __shfl_xor(s, 2);  s += __shfl_xor(s, 4);
    s += __shfl_xor(s, 8);  s += __shfl_xor(s, 16);
    if (t31 == 0) scores[(size_t)blockIdx.x * 8 + nl] = s + ab3[0];
}

// ---------------------------------------------------------------------------
// K2: softmax max + sum(exp) over 16384 scores, single block
// ---------------------------------------------------------------------------
__global__ __launch_bounds__(1024) void k_softmax_red(
    const float* __restrict__ scores, float* __restrict__ red)
{
    __shared__ float sm[1024];
    const int tid = threadIdx.x;
    float m = -3.4e38f;
    for (int i = tid; i < N_NODES; i += 1024) m = fmaxf(m, scores[i]);
    sm[tid] = m; __syncthreads();
    for (int s = 512; s > 0; s >>= 1) {
        if (tid < s) sm[tid] = fmaxf(sm[tid], sm[tid + s]);
        __syncthreads();
    }
    m = sm[0];
    __syncthreads();
    float acc = 0.f;
    for (int i = tid; i < N_NODES; i += 1024) acc += expf(scores[i] - m);
    sm[tid] = acc; __syncthreads();
    for (int s = 512; s > 0; s >>= 1) {
        if (tid < s) sm[tid] += sm[tid + s];
        __syncthreads();
    }
    if (tid == 0) { red[0] = m; red[1] = sm[0]; }
}

// ---------------------------------------------------------------------------
// K3: attn = softmax(scores); wfT(bf16, transposed [32][16384]); gc = sum(wf)
// ---------------------------------------------------------------------------
__global__ __launch_bounds__(256) void k_attn_wf(
    const float* __restrict__ scores, const float* __restrict__ red,
    const float* __restrict__ x, float* __restrict__ attn,
    unsigned short* __restrict__ wfT, float* __restrict__ gc)
{
    const int n = blockIdx.x * 256 + threadIdx.x;
    const float m = red[0], s = red[1];
    const float a = expf(scores[n] - m) / s;
    attn[n] = a;

    float wv[32];
    const float4* xr = (const float4*)(x + (size_t)n * 32);
    #pragma unroll
    for (int q = 0; q < 8; ++q) {
        float4 v = xr[q];
        wv[q*4+0] = v.x * a; wv[q*4+1] = v.y * a;
        wv[q*4+2] = v.z * a; wv[q*4+3] = v.w * a;
    }
    #pragma unroll
    for (int c = 0; c < 32; ++c)
        wfT[(size_t)c * N_NODES + n] = f2bf(wv[c]);   // coalesced per c

    const int lane = threadIdx.x & 63;
    #pragma unroll
    for (int c = 0; c < 32; ++c) {
        float v = wv[c];
        v += __shfl_xor(v, 1);  v += __shfl_xor(v, 2);  v += __shfl_xor(v, 4);
        v += __shfl_xor(v, 8);  v += __shfl_xor(v, 16); v += __shfl_xor(v, 32);
        if (lane == 0) atomicAdd(&gc[c], v);
    }
}

// ---------------------------------------------------------------------------
// K5 v5: B-slice staged in LDS ONCE per block; steady-state loop has exactly
// ONE vmem stream (A). Grid = 256 row-blocks x 32 col-splits of 512.
// Per wave: 16 rows, 8 tiles of 64 cols, 4-deep A register prefetch,
// wave-private LDS A double-buffer (no barriers in loop).
// Block partials -> partials[bid] (reduced in k_mlp1), no global atomics.
// ---------------------------------------------------------------------------
__device__ __forceinline__ void a_issue(const float* __restrict__ A,
    int i0, int gcol, int lane, f4v (&dst)[4])
{
    const int rlo = lane >> 4, c16 = (lane & 15) * 4;
    #pragma unroll
    for (int r = 0; r < 4; ++r)
        dst[r] = __builtin_nontemporal_load(
            (const f4v*)(A + (size_t)(i0 + 4*r + rlo) * N_NODES + gcol + c16));
}

__device__ __forceinline__ void a_write(char* wb, int lane, const f4v (&src)[4])
{
    const int rlo = lane >> 4, cb = (lane & 15) * 8;
    #pragma unroll
    for (int r = 0; r < 4; ++r) {
        const int row = 4*r + rlo;
        s16x4 w;
        w[0] = (short)f2bf(src[r][0]); w[1] = (short)f2bf(src[r][1]);
        w[2] = (short)f2bf(src[r][2]); w[3] = (short)f2bf(src[r][3]);
        *(s16x4*)(wb + row*128 + (cb ^ ((row & 7) << 4))) = w;
    }
}

template<int T>
__device__ __forceinline__ void ctx_step(
    const float* __restrict__ A, const unsigned short* __restrict__ sB_u,
    char* wbase, int i0, int gcol0, int lane, int q, int r16,
    f4v (&iss)[4], f4v (&wr)[4], f32x4& acc0, f32x4& acc1)
{
    const char* sBb = (const char*)sB_u;
    const int swz = (r16 & 7) << 4;
    // B fragments for tile T from LDS (staged once per block)
    short8 b00 = *(const short8*)(sBb + r16*1024      + ((T*128      + q*16) ^ swz));
    short8 b01 = *(const short8*)(sBb + r16*1024      + ((T*128 + 64 + q*16) ^ swz));
    short8 b10 = *(const short8*)(sBb + (r16+16)*1024 + ((T*128      + q*16) ^ swz));
    short8 b11 = *(const short8*)(sBb + (r16+16)*1024 + ((T*128 + 64 + q*16) ^ swz));
    // issue A(T+4): only vmem in the loop -> in-order retire works for us
    if constexpr (T + 4 < 8)
        a_issue(A, i0, gcol0 + (T + 4) * 64, lane, iss);
    // A fragments from wave-private LDS buffer (T&1)
    const char* ab = wbase + (T & 1) * 2048;
    short8 av0 = *(const short8*)(ab + r16*128 + ((     q*16) ^ swz));
    short8 av1 = *(const short8*)(ab + r16*128 + ((64 + q*16) ^ swz));
    acc0 = __builtin_amdgcn_mfma_f32_16x16x32_bf16(av0, b00, acc0, 0, 0, 0);
    acc1 = __builtin_amdgcn_mfma_f32_16x16x32_bf16(av0, b10, acc1, 0, 0, 0);
    acc0 = __builtin_amdgcn_mfma_f32_16x16x32_bf16(av1, b01, acc0, 0, 0, 0);
    acc1 = __builtin_amdgcn_mfma_f32_16x16x32_bf16(av1, b11, acc1, 0, 0, 0);
    // cvt + write A(T+1) (waits its batch only; T+2..T+4 stay in flight)
    if constexpr (T + 1 < 8)
        a_write(wbase + ((T + 1) & 1) * 2048, lane, wr);
    __builtin_amdgcn_sched_barrier(0);
}

__global__ __launch_bounds__(256, 3) void k_context(
    const float* __restrict__ A, const unsigned short* __restrict__ wfT,
    const float* __restrict__ x, const float* __restrict__ attn,
    float* __restrict__ partials)
{
    __shared__ unsigned short sB_u[32 * 512];   // 32 KB, XOR-swizzled
    __shared__ short sA[4][2][1024];            // 16 KB: per-wave double buffer
    __shared__ float sRed[4];

    const int tid  = threadIdx.x;
    const int wid  = tid >> 6, lane = tid & 63;
    const int rb   = blockIdx.x & 255;   // 256 row-blocks of 64 rows
    const int js   = blockIdx.x >> 8;    // 32 col-splits of 512
    const int i0   = rb * 64 + wid * 16;
    const int gcol0 = js * 512;

    const int q   = lane >> 4;
    const int r16 = lane & 15;
    char* wbase = (char*)sA[wid];

    f32x4 acc0 = {0.f, 0.f, 0.f, 0.f};
    f32x4 acc1 = {0.f, 0.f, 0.f, 0.f};

    f4v s0[4], s1[4], s2[4], s3[4];

    // prologue: get the HBM stream going first
    a_issue(A, i0, gcol0,       lane, s0);
    a_issue(A, i0, gcol0 + 64,  lane, s1);
    a_issue(A, i0, gcol0 + 128, lane, s2);
    a_issue(A, i0, gcol0 + 192, lane, s3);

    // stage B slice: 32 rows x 512 cols bf16, XOR-swizzled
    {
        const int row = tid >> 3;
        const unsigned short* gB = wfT + (size_t)row * N_NODES + gcol0;
        char* lB = (char*)sB_u + row * 1024;
        #pragma unroll
        for (int c = 0; c < 8; ++c) {
            const int chunk = (tid & 7) + 8 * c;
            short8 v = *(const short8*)(gB + chunk * 8);
            *(short8*)(lB + ((chunk * 16) ^ ((row & 7) << 4))) = v;
        }
    }
    __syncthreads();
    a_write(wbase, lane, s0);    // tile 0 -> buf 0 (wave-private)
    __builtin_amdgcn_sched_barrier(0);

    ctx_step<0>(A, sB_u, wbase, i0, gcol0, lane, q, r16, s0, s1, acc0, acc1);
    ctx_step<1>(A, sB_u, wbase, i0, gcol0, lane, q, r16, s1, s2, acc0, acc1);
    ctx_step<2>(A, sB_u, wbase, i0, gcol0, lane, q, r16, s2, s3, acc0, acc1);
    ctx_step<3>(A, sB_u, wbase, i0, gcol0, lane, q, r16, s3, s0, acc0, acc1);
    ctx_step<4>(A, sB_u, wbase, i0, gcol0, lane, q, r16, s0, s1, acc0, acc1);
    ctx_step<5>(A, sB_u, wbase, i0, gcol0, lane, q, r16, s1, s2, acc0, acc1);
    ctx_step<6>(A, sB_u, wbase, i0, gcol0, lane, q, r16, s2, s3, acc0, acc1);
    ctx_step<7>(A, sB_u, wbase, i0, gcol0, lane, q, r16, s3, s0, acc0, acc1);

    // epilogue: D[row=q*4+r, col=r16]; dot with wf = x*attn, reduce
    float partial = 0.f;
    #pragma unroll
    for (int r = 0; r < 4; ++r) {
        const int i = i0 + q * 4 + r;
        const float a = attn[i];
        partial += acc0[r] * (x[(size_t)i * 32 + r16]      * a);
        partial += acc1[r] * (x[(size_t)i * 32 + 16 + r16] * a);
    }
    partial += __shfl_xor(partial, 1);  partial += __shfl_xor(partial, 2);
    partial += __shfl_xor(partial, 4);  partial += __shfl_xor(partial, 8);
    partial += __shfl_xor(partial, 16); partial += __shfl_xor(partial, 32);
    if (lane == 0) sRed[wid] = partial;
    __syncthreads();
    if (tid == 0) partials[blockIdx.x] = (sRed[0] + sRed[1]) + (sRed[2] + sRed[3]);
}

// ---------------------------------------------------------------------------
// K6a: reduce partials[8192] -> cs; h1 for gc and gc2 = gc + 0.001*(cs/N)
// ---------------------------------------------------------------------------
__global__ __launch_bounds__(1024) void k_mlp1(
    const float* __restrict__ gc, const float* __restrict__ partials,
    const float* __restrict__ w1, const float* __restrict__ b1,
    float* __restrict__ h1ab)
{
    __shared__ float sm[1024];
    __shared__ float g1[32], g2[32];
    const int t = threadIdx.x;
    float acc = 0.f;
    #pragma unroll
    for (int i = 0; i < 8; ++i) acc += partials[t + 1024 * i];
    sm[t] = acc; __syncthreads();
    for (int s = 512; s > 0; s >>= 1) {
        if (t < s) sm[t] += sm[t + s];
        __syncthreads();
    }
    if (t < 32) {
        float cs = sm[0] * (1.0f / 16384.0f);
        g1[t] = gc[t];
        g2[t] = gc[t] + 0.001f * cs;
    }
    __syncthreads();
    float s1 = b1[t], s2 = b1[t];
    #pragma unroll
    for (int c = 0; c < 32; ++c) {
        float wv = w1[(size_t)c * 1024 + t];
        s1 += g1[c] * wv;
        s2 += g2[c] * wv;
    }
    h1ab[t]        = fmaxf(s1, 0.f);
    h1ab[1024 + t] = fmaxf(s2, 0.f);
}

// ---------------------------------------------------------------------------
// K6b: h2 = relu(h1 @ w2 + b2), split-K (16 K-groups of 64), LDS tree reduce.
// ---------------------------------------------------------------------------
__global__ __launch_bounds__(256) void k_mlp2(
    const float* __restrict__ h1ab, const float* __restrict__ w2,
    const float* __restrict__ b2, float* __restrict__ h2ab)
{
    __shared__ float h1s[1024];
    __shared__ float sm[256];
    const int v   = blockIdx.x & 1;
    const int ob  = blockIdx.x >> 1;      // 0..63
    const int tid = threadIdx.x;
    const int o   = tid & 15, g = tid >> 4;
    for (int i = tid; i < 1024; i += 256) h1s[i] = h1ab[v * 1024 + i];
    __syncthreads();
    const float* wp = w2 + (size_t)(g * 64) * 1024 + ob * 16 + o;
    float acc = 0.f;
    #pragma unroll 8
    for (int k = 0; k < 64; ++k)
        acc += h1s[g * 64 + k] * wp[(size_t)k * 1024];
    sm[tid] = acc;
    __syncthreads();
    if (tid < 16) {
        float s = b2[ob * 16 + tid];
        #pragma unroll
        for (int g2 = 0; g2 < 16; ++g2) s += sm[g2 * 16 + tid];
        h2ab[v * 1024 + ob * 16 + tid] = fmaxf(s, 0.f);
    }
}

// ---------------------------------------------------------------------------
// K6c: out = relu(h2a@w3+b3) + 0.002*relu(h2b@w3+b3), split-K, both variants.
// ---------------------------------------------------------------------------
__global__ __launch_bounds__(512) void k_mlp3(
    const float* __restrict__ h2ab, const float* __restrict__ w3,
    const float* __restrict__ b3, float* __restrict__ out)
{
    __shared__ float sm[512];
    const int tid = threadIdx.x;
    const int v   = tid >> 8;
    const int g   = (tid >> 4) & 15;
    const int o   = tid & 15;
    const int ob  = blockIdx.x;           // 16 blocks x 16 outputs
    const float* hp = h2ab + v * 1024 + g * 64;
    const float* wp = w3 + (size_t)(g * 64) * 256 + ob * 16 + o;
    float acc = 0.f;
    #pragma unroll 8
    for (int k = 0; k < 64; ++k)
        acc += hp[k] * wp[(size_t)k * 256];
    sm[tid] = acc;
    __syncthreads();
    if (tid < 16) {
        float pa = b3[ob * 16 + tid], pb = pa;
        #pragma unroll
        for (int g2 = 0; g2 < 16; ++g2) {
            pa += sm[g2 * 16 + tid];
            pb += sm[256 + g2 * 16 + tid];
        }
        out[ob * 16 + tid] = fmaxf(pa, 0.f) + 0.002f * fmaxf(pb, 0.f);
    }
}

// ---------------------------------------------------------------------------
extern "C" void kernel_launch(void* const* d_in, const int* in_sizes, int n_in,
                              void* d_out, int out_size, void* d_ws, size_t ws_size,
                              hipStream_t stream)
{
    const float* x   = (const float*)d_in[0];
    const float* A   = (const float*)d_in[1];
    const float* gw1 = (const float*)d_in[2];
    const float* gb1 = (const float*)d_in[3];
    const float* gw2 = (const float*)d_in[4];
    const float* gb2 = (const float*)d_in[5];
    const float* gw3 = (const float*)d_in[6];
    const float* gb3 = (const float*)d_in[7];
    const float* aw1 = (const float*)d_in[8];
    const float* ab1 = (const float*)d_in[9];
    const float* aw2 = (const float*)d_in[10];
    const float* ab2 = (const float*)d_in[11];
    const float* aw3 = (const float*)d_in[12];
    const float* ab3 = (const float*)d_in[13];
    float* out = (float*)d_out;

    char* ws = (char*)d_ws;
    float* scores   = (float*)(ws + 0);            // 16384 f32
    float* attn     = (float*)(ws + 65536);        // 16384 f32
    float* red      = (float*)(ws + 131072);       // 2 f32 (max, sumexp)
    float* gc       = (float*)(ws + 131328);       // 32 f32
    float* h1ab     = (float*)(ws + 131584);       // 2048 f32
    float* h2ab     = (float*)(ws + 139776);       // 2048 f32
    float* partials = (float*)(ws + 163840);       // 8192 f32
    unsigned short* wfT = (unsigned short*)(ws + 262144);  // 32*16384 bf16 = 1 MB

    k_zero       <<<1,    32,   0, stream>>>(gc);
    k_attn_scores<<<N_NODES/8, 256, 0, stream>>>(x, aw1, ab1, aw2, ab2, aw3, ab3, scores);
    k_softmax_red<<<1,    1024, 0, stream>>>(scores, red);
    k_attn_wf    <<<N_NODES/256, 256, 0, stream>>>(scores, red, x, attn, wfT, gc);
    k_context    <<<8192, 256,  0, stream>>>(A, wfT, x, attn, partials);
    k_mlp1       <<<1,    1024, 0, stream>>>(gc, partials, gw1, gb1, h1ab);
    k_mlp2       <<<128,  256,  0, stream>>>(h1ab, gw2, gb2, h2ab);
    k_mlp3       <<<16,   512,  0, stream>>>(h2ab, gw3, gb3, out);
}

// Round 10
// 295.763 us; speedup vs baseline: 1.9014x; 1.0308x over previous
//
#include <hip/hip_runtime.h>
#include <hip/hip_bf16.h>
#include <math.h>

#define N_NODES 16384
#define C_IN 32

typedef __attribute__((ext_vector_type(8))) short short8;
typedef __attribute__((ext_vector_type(4))) short s16x4;
typedef __attribute__((ext_vector_type(4))) float f32x4;
typedef __attribute__((ext_vector_type(4))) float f4v;

__device__ __forceinline__ unsigned short f2bf(float f) {
    unsigned u = __float_as_uint(f);
    u = u + 0x7fffu + ((u >> 16) & 1u);   // RNE to bf16
    return (unsigned short)(u >> 16);
}

// ---------------------------------------------------------------------------
// K0: zero gc[32]
// ---------------------------------------------------------------------------
__global__ void k_zero(float* __restrict__ p) {
    p[threadIdx.x] = 0.f;
}

// ---------------------------------------------------------------------------
// K1: attention scores.  8 nodes per 256-thread block.
// ---------------------------------------------------------------------------
__global__ __launch_bounds__(256) void k_attn_scores(
    const float* __restrict__ x,
    const float* __restrict__ aw1, const float* __restrict__ ab1,
    const float* __restrict__ aw2, const float* __restrict__ ab2,
    const float* __restrict__ aw3, const float* __restrict__ ab3,
    float* __restrict__ scores)
{
    __shared__ float w1s[4096];   // [32][128]
    __shared__ float w2s[8192];   // [128][64]
    __shared__ float b1s[128];
    __shared__ float b2s[64];
    __shared__ float w3s[64];
    __shared__ float xs[256];     // 8 nodes x 32 ch
    __shared__ float h1s[1024];   // 8 nodes x 128

    const int tid = threadIdx.x;
    for (int i = tid; i < 4096; i += 256) w1s[i] = aw1[i];
    for (int i = tid; i < 8192; i += 256) w2s[i] = aw2[i];
    if (tid < 128) b1s[tid] = ab1[tid];
    if (tid < 64)  { b2s[tid] = ab2[tid]; w3s[tid] = aw3[tid]; }
    xs[tid] = x[(size_t)blockIdx.x * 256 + tid];
    __syncthreads();

    const int nl  = tid >> 5;   // node 0..7
    const int t31 = tid & 31;

    float a0 = b1s[t31*4+0], a1 = b1s[t31*4+1], a2 = b1s[t31*4+2], a3 = b1s[t31*4+3];
    #pragma unroll
    for (int c = 0; c < 32; ++c) {
        float xv = xs[nl*32 + c];
        float4 w = *(const float4*)&w1s[c*128 + t31*4];
        a0 += xv * w.x; a1 += xv * w.y; a2 += xv * w.z; a3 += xv * w.w;
    }
    *(float4*)&h1s[nl*128 + t31*4] =
        make_float4(fmaxf(a0,0.f), fmaxf(a1,0.f), fmaxf(a2,0.f), fmaxf(a3,0.f));
    __syncthreads();

    float c0 = b2s[t31*2], c1 = b2s[t31*2 + 1];
    #pragma unroll 8
    for (int o = 0; o < 128; ++o) {
        float hv = h1s[nl*128 + o];
        float2 w = *(const float2*)&w2s[o*64 + t31*2];
        c0 += hv * w.x;
        c1 += hv * w.y;
    }
    float s = fmaxf(c0, 0.f) * w3s[t31*2] + fmaxf(c1, 0.f) * w3s[t31*2 + 1];
    s += __shfl_xor(s, 1);  s += __shfl_xor(s, 2);  s += __shfl_xor(s, 4);
    s += __shfl_xor(s, 8);  s += __shfl_xor(s, 16);
    if (t31 == 0) scores[(size_t)blockIdx.x * 8 + nl] = s + ab3[0];
}

// ---------------------------------------------------------------------------
// K2: softmax max + sum(exp) over 16384 scores, single block
// ---------------------------------------------------------------------------
__global__ __launch_bounds__(1024) void k_softmax_red(
    const float* __restrict__ scores, float* __restrict__ red)
{
    __shared__ float sm[1024];
    const int tid = threadIdx.x;
    float m = -3.4e38f;
    for (int i = tid; i < N_NODES; i += 1024) m = fmaxf(m, scores[i]);
    sm[tid] = m; __syncthreads();
    for (int s = 512; s > 0; s >>= 1) {
        if (tid < s) sm[tid] = fmaxf(sm[tid], sm[tid + s]);
        __syncthreads();
    }
    m = sm[0];
    __syncthreads();
    float acc = 0.f;
    for (int i = tid; i < N_NODES; i += 1024) acc += expf(scores[i] - m);
    sm[tid] = acc; __syncthreads();
    for (int s = 512; s > 0; s >>= 1) {
        if (tid < s) sm[tid] += sm[tid + s];
        __syncthreads();
    }
    if (tid == 0) { red[0] = m; red[1] = sm[0]; }
}

// ---------------------------------------------------------------------------
// K3: attn = softmax(scores); wfT(bf16, transposed [32][16384]); gc = sum(wf)
// ---------------------------------------------------------------------------
__global__ __launch_bounds__(256) void k_attn_wf(
    const float* __restrict__ scores, const float* __restrict__ red,
    const float* __restrict__ x, float* __restrict__ attn,
    unsigned short* __restrict__ wfT, float* __restrict__ gc)
{
    const int n = blockIdx.x * 256 + threadIdx.x;
    const float m = red[0], s = red[1];
    const float a = expf(scores[n] - m) / s;
    attn[n] = a;

    float wv[32];
    const float4* xr = (const float4*)(x + (size_t)n * 32);
    #pragma unroll
    for (int q = 0; q < 8; ++q) {
        float4 v = xr[q];
        wv[q*4+0] = v.x * a; wv[q*4+1] = v.y * a;
        wv[q*4+2] = v.z * a; wv[q*4+3] = v.w * a;
    }
    #pragma unroll
    for (int c = 0; c < 32; ++c)
        wfT[(size_t)c * N_NODES + n] = f2bf(wv[c]);   // coalesced per c

    const int lane = threadIdx.x & 63;
    #pragma unroll
    for (int c = 0; c < 32; ++c) {
        float v = wv[c];
        v += __shfl_xor(v, 1);  v += __shfl_xor(v, 2);  v += __shfl_xor(v, 4);
        v += __shfl_xor(v, 8);  v += __shfl_xor(v, 16); v += __shfl_xor(v, 32);
        if (lane == 0) atomicAdd(&gc[c], v);
    }
}

// ---------------------------------------------------------------------------
// K5 v6: bulk + TLP. Grid = 256 row-blocks x 64 col-splits of 256 cols.
// ONE load batch per block: each wave stages its 16 rows with one
// full-row 1KB-contiguous instruction per row (single DRAM page burst);
// B slice (32x256 bf16 = 16KB) staged once. No loop, no double buffer --
// in-order vmcnt retire is harmless with a single batch; latency hiding
// comes from 3 blocks/CU TLP. A region is wave-private (no barrier needed
// between its LDS write and read; only B needs the one __syncthreads).
// ---------------------------------------------------------------------------
__global__ __launch_bounds__(256, 3) void k_context(
    const float* __restrict__ A, const unsigned short* __restrict__ wfT,
    const float* __restrict__ x, const float* __restrict__ attn,
    float* __restrict__ partials)
{
    __shared__ unsigned short sB_u[32 * 256];    // 16 KB, XOR-swizzled
    __shared__ short sA[4][16 * 256];            // 32 KB: per-wave 16 rows x 256
    __shared__ float sRed[4];

    const int tid   = threadIdx.x;
    const int wid   = tid >> 6, lane = tid & 63;
    const int rb    = blockIdx.x & 255;   // 256 row-blocks of 64 rows
    const int js    = blockIdx.x >> 8;    // 64 col-splits of 256
    const int i0    = rb * 64 + wid * 16;
    const int gcol0 = js * 256;

    const int q   = lane >> 4;
    const int r16 = lane & 15;
    char* wbase = (char*)sA[wid];

    // ---- issue A loads FIRST: 16 instructions, each one full row = 1KB ----
    f4v av[16];
    #pragma unroll
    for (int r = 0; r < 16; ++r)
        av[r] = __builtin_nontemporal_load(
            (const f4v*)(A + (size_t)(i0 + r) * N_NODES + gcol0 + lane * 4));

    // ---- stage B slice (L2-resident wfT): 32 rows x 512B, swizzled ----
    {
        const int row = tid >> 3;                 // 0..31
        const unsigned short* gB = wfT + (size_t)row * N_NODES + gcol0;
        char* lB = (char*)sB_u + row * 512;
        #pragma unroll
        for (int c = 0; c < 4; ++c) {
            const int chunk = (tid & 7) + 8 * c;  // 0..31, 16B each
            short8 v = *(const short8*)(gB + chunk * 8);
            *(short8*)(lB + ((chunk * 16) ^ ((row & 7) << 4))) = v;
        }
    }
    __syncthreads();   // B visible to all waves (also implies vmcnt drain of A)

    // ---- cvt + write A rows into wave-private LDS (8B/lane, swizzled) ----
    #pragma unroll
    for (int r = 0; r < 16; ++r) {
        s16x4 w;
        w[0] = (short)f2bf(av[r][0]); w[1] = (short)f2bf(av[r][1]);
        w[2] = (short)f2bf(av[r][2]); w[3] = (short)f2bf(av[r][3]);
        *(s16x4*)(wbase + r * 512 + ((lane * 8) ^ ((r & 7) << 4))) = w;
    }

    // ---- MFMA: 8 k-slices x 2 channel-halves (wave-private A, shared B) ----
    f32x4 acc0 = {0.f, 0.f, 0.f, 0.f};
    f32x4 acc1 = {0.f, 0.f, 0.f, 0.f};
    const int swzA = (r16 & 7) << 4;
    const char* sBb = (const char*)sB_u;
    #pragma unroll
    for (int kk = 0; kk < 8; ++kk) {
        const int fo = kk * 64 + q * 16;
        short8 afr = *(const short8*)(wbase + r16 * 512 + (fo ^ swzA));
        short8 b0  = *(const short8*)(sBb + r16 * 512        + (fo ^ swzA));
        short8 b1  = *(const short8*)(sBb + (r16 + 16) * 512 + (fo ^ swzA));
        // (r16+16)&7 == r16&7 (16 ≡ 0 mod 8) -> same swizzle key for both B rows
        acc0 = __builtin_amdgcn_mfma_f32_16x16x32_bf16(afr, b0, acc0, 0, 0, 0);
        acc1 = __builtin_amdgcn_mfma_f32_16x16x32_bf16(afr, b1, acc1, 0, 0, 0);
    }

    // ---- epilogue: D[row=q*4+r, col=r16]; dot with wf = x*attn, reduce ----
    float partial = 0.f;
    #pragma unroll
    for (int r = 0; r < 4; ++r) {
        const int i = i0 + q * 4 + r;
        const float a = attn[i];
        partial += acc0[r] * (x[(size_t)i * 32 + r16]      * a);
        partial += acc1[r] * (x[(size_t)i * 32 + 16 + r16] * a);
    }
    partial += __shfl_xor(partial, 1);  partial += __shfl_xor(partial, 2);
    partial += __shfl_xor(partial, 4);  partial += __shfl_xor(partial, 8);
    partial += __shfl_xor(partial, 16); partial += __shfl_xor(partial, 32);
    if (lane == 0) sRed[wid] = partial;
    __syncthreads();
    if (tid == 0) partials[blockIdx.x] = (sRed[0] + sRed[1]) + (sRed[2] + sRed[3]);
}

// ---------------------------------------------------------------------------
// K6a: reduce partials[16384] -> cs; h1 for gc and gc2 = gc + 0.001*(cs/N)
// ---------------------------------------------------------------------------
__global__ __launch_bounds__(1024) void k_mlp1(
    const float* __restrict__ gc, const float* __restrict__ partials,
    const float* __restrict__ w1, const float* __restrict__ b1,
    float* __restrict__ h1ab)
{
    __shared__ float sm[1024];
    __shared__ float g1[32], g2[32];
    const int t = threadIdx.x;
    float acc = 0.f;
    #pragma unroll
    for (int i = 0; i < 16; ++i) acc += partials[t + 1024 * i];
    sm[t] = acc; __syncthreads();
    for (int s = 512; s > 0; s >>= 1) {
        if (t < s) sm[t] += sm[t + s];
        __syncthreads();
    }
    if (t < 32) {
        float cs = sm[0] * (1.0f / 16384.0f);
        g1[t] = gc[t];
        g2[t] = gc[t] + 0.001f * cs;
    }
    __syncthreads();
    float s1 = b1[t], s2 = b1[t];
    #pragma unroll
    for (int c = 0; c < 32; ++c) {
        float wv = w1[(size_t)c * 1024 + t];
        s1 += g1[c] * wv;
        s2 += g2[c] * wv;
    }
    h1ab[t]        = fmaxf(s1, 0.f);
    h1ab[1024 + t] = fmaxf(s2, 0.f);
}

// ---------------------------------------------------------------------------
// K6b: h2 = relu(h1 @ w2 + b2), split-K (16 K-groups of 64), LDS tree reduce.
// ---------------------------------------------------------------------------
__global__ __launch_bounds__(256) void k_mlp2(
    const float* __restrict__ h1ab, const float* __restrict__ w2,
    const float* __restrict__ b2, float* __restrict__ h2ab)
{
    __shared__ float h1s[1024];
    __shared__ float sm[256];
    const int v   = blockIdx.x & 1;
    const int ob  = blockIdx.x >> 1;      // 0..63
    const int tid = threadIdx.x;
    const int o   = tid & 15, g = tid >> 4;
    for (int i = tid; i < 1024; i += 256) h1s[i] = h1ab[v * 1024 + i];
    __syncthreads();
    const float* wp = w2 + (size_t)(g * 64) * 1024 + ob * 16 + o;
    float acc = 0.f;
    #pragma unroll 8
    for (int k = 0; k < 64; ++k)
        acc += h1s[g * 64 + k] * wp[(size_t)k * 1024];
    sm[tid] = acc;
    __syncthreads();
    if (tid < 16) {
        float s = b2[ob * 16 + tid];
        #pragma unroll
        for (int g2 = 0; g2 < 16; ++g2) s += sm[g2 * 16 + tid];
        h2ab[v * 1024 + ob * 16 + tid] = fmaxf(s, 0.f);
    }
}

// ---------------------------------------------------------------------------
// K6c: out = relu(h2a@w3+b3) + 0.002*relu(h2b@w3+b3), split-K, both variants.
// ---------------------------------------------------------------------------
__global__ __launch_bounds__(512) void k_mlp3(
    const float* __restrict__ h2ab, const float* __restrict__ w3,
    const float* __restrict__ b3, float* __restrict__ out)
{
    __shared__ float sm[512];
    const int tid = threadIdx.x;
    const int v   = tid >> 8;
    const int g   = (tid >> 4) & 15;
    const int o   = tid & 15;
    const int ob  = blockIdx.x;           // 16 blocks x 16 outputs
    const float* hp = h2ab + v * 1024 + g * 64;
    const float* wp = w3 + (size_t)(g * 64) * 256 + ob * 16 + o;
    float acc = 0.f;
    #pragma unroll 8
    for (int k = 0; k < 64; ++k)
        acc += hp[k] * wp[(size_t)k * 256];
    sm[tid] = acc;
    __syncthreads();
    if (tid < 16) {
        float pa = b3[ob * 16 + tid], pb = pa;
        #pragma unroll
        for (int g2 = 0; g2 < 16; ++g2) {
            pa += sm[g2 * 16 + tid];
            pb += sm[256 + g2 * 16 + tid];
        }
        out[ob * 16 + tid] = fmaxf(pa, 0.f) + 0.002f * fmaxf(pb, 0.f);
    }
}

// ---------------------------------------------------------------------------
extern "C" void kernel_launch(void* const* d_in, const int* in_sizes, int n_in,
                              void* d_out, int out_size, void* d_ws, size_t ws_size,
                              hipStream_t stream)
{
    const float* x   = (const float*)d_in[0];
    const float* A   = (const float*)d_in[1];
    const float* gw1 = (const float*)d_in[2];
    const float* gb1 = (const float*)d_in[3];
    const float* gw2 = (const float*)d_in[4];
    const float* gb2 = (const float*)d_in[5];
    const float* gw3 = (const float*)d_in[6];
    const float* gb3 = (const float*)d_in[7];
    const float* aw1 = (const float*)d_in[8];
    const float* ab1 = (const float*)d_in[9];
    const float* aw2 = (const float*)d_in[10];
    const float* ab2 = (const float*)d_in[11];
    const float* aw3 = (const float*)d_in[12];
    const float* ab3 = (const float*)d_in[13];
    float* out = (float*)d_out;

    char* ws = (char*)d_ws;
    float* scores   = (float*)(ws + 0);            // 16384 f32
    float* attn     = (float*)(ws + 65536);        // 16384 f32
    float* red      = (float*)(ws + 131072);       // 2 f32 (max, sumexp)
    float* gc       = (float*)(ws + 131328);       // 32 f32
    float* h1ab     = (float*)(ws + 131584);       // 2048 f32
    float* h2ab     = (float*)(ws + 139776);       // 2048 f32
    float* partials = (float*)(ws + 163840);       // 16384 f32 (ends 229376)
    unsigned short* wfT = (unsigned short*)(ws + 262144);  // 32*16384 bf16 = 1 MB

    k_zero       <<<1,    32,   0, stream>>>(gc);
    k_attn_scores<<<N_NODES/8, 256, 0, stream>>>(x, aw1, ab1, aw2, ab2, aw3, ab3, scores);
    k_softmax_red<<<1,    1024, 0, stream>>>(scores, red);
    k_attn_wf    <<<N_NODES/256, 256, 0, stream>>>(scores, red, x, attn, wfT, gc);
    k_context    <<<16384, 256, 0, stream>>>(A, wfT, x, attn, partials);
    k_mlp1       <<<1,    1024, 0, stream>>>(gc, partials, gw1, gb1, h1ab);
    k_mlp2       <<<128,  256,  0, stream>>>(h1ab, gw2, gb2, h2ab);
    k_mlp3       <<<16,   512,  0, stream>>>(h2ab, gw3, gb3, out);
}

// Round 13
// 290.203 us; speedup vs baseline: 1.9378x; 1.0192x over previous
//
#include <hip/hip_runtime.h>
#include <hip/hip_bf16.h>
#include <math.h>

#define N_NODES 16384
#define C_IN 32

typedef __attribute__((ext_vector_type(8))) short short8;
typedef __attribute__((ext_vector_type(4))) short s16x4;
typedef __attribute__((ext_vector_type(4))) float f32x4;
typedef __attribute__((ext_vector_type(4))) float f4v;

__device__ __forceinline__ unsigned short f2bf(float f) {
    unsigned u = __float_as_uint(f);
    u = u + 0x7fffu + ((u >> 16) & 1u);   // RNE to bf16
    return (unsigned short)(u >> 16);
}

// ---------------------------------------------------------------------------
// K0: zero gc[32]
// ---------------------------------------------------------------------------
__global__ void k_zero(float* __restrict__ p) {
    p[threadIdx.x] = 0.f;
}

// ---------------------------------------------------------------------------
// K1: attention scores.  8 nodes per 256-thread block.
// ---------------------------------------------------------------------------
__global__ __launch_bounds__(256) void k_attn_scores(
    const float* __restrict__ x,
    const float* __restrict__ aw1, const float* __restrict__ ab1,
    const float* __restrict__ aw2, const float* __restrict__ ab2,
    const float* __restrict__ aw3, const float* __restrict__ ab3,
    float* __restrict__ scores)
{
    __shared__ float w1s[4096];   // [32][128]
    __shared__ float w2s[8192];   // [128][64]
    __shared__ float b1s[128];
    __shared__ float b2s[64];
    __shared__ float w3s[64];
    __shared__ float xs[256];     // 8 nodes x 32 ch
    __shared__ float h1s[1024];   // 8 nodes x 128

    const int tid = threadIdx.x;
    for (int i = tid; i < 4096; i += 256) w1s[i] = aw1[i];
    for (int i = tid; i < 8192; i += 256) w2s[i] = aw2[i];
    if (tid < 128) b1s[tid] = ab1[tid];
    if (tid < 64)  { b2s[tid] = ab2[tid]; w3s[tid] = aw3[tid]; }
    xs[tid] = x[(size_t)blockIdx.x * 256 + tid];
    __syncthreads();

    const int nl  = tid >> 5;   // node 0..7
    const int t31 = tid & 31;

    float a0 = b1s[t31*4+0], a1 = b1s[t31*4+1], a2 = b1s[t31*4+2], a3 = b1s[t31*4+3];
    #pragma unroll
    for (int c = 0; c < 32; ++c) {
        float xv = xs[nl*32 + c];
        float4 w = *(const float4*)&w1s[c*128 + t31*4];
        a0 += xv * w.x; a1 += xv * w.y; a2 += xv * w.z; a3 += xv * w.w;
    }
    *(float4*)&h1s[nl*128 + t31*4] =
        make_float4(fmaxf(a0,0.f), fmaxf(a1,0.f), fmaxf(a2,0.f), fmaxf(a3,0.f));
    __syncthreads();

    float c0 = b2s[t31*2], c1 = b2s[t31*2 + 1];
    #pragma unroll 8
    for (int o = 0; o < 128; ++o) {
        float hv = h1s[nl*128 + o];
        float2 w = *(const float2*)&w2s[o*64 + t31*2];
        c0 += hv * w.x;
        c1 += hv * w.y;
    }
    float s = fmaxf(c0, 0.f) * w3s[t31*2] + fmaxf(c1, 0.f) * w3s[t31*2 + 1];
    s += __shfl_xor(s, 1);  s += __shfl_xor(s, 2);  s += __shfl_xor(s, 4);
    s += __shfl_xor(s, 8);  s += __shfl_xor(s, 16);
    if (t31 == 0) scores[(size_t)blockIdx.x * 8 + nl] = s + ab3[0];
}

// ---------------------------------------------------------------------------
// K2: softmax max + sum(exp) over 16384 scores, single block
// ---------------------------------------------------------------------------
__global__ __launch_bounds__(1024) void k_softmax_red(
    const float* __restrict__ scores, float* __restrict__ red)
{
    __shared__ float sm[1024];
    const int tid = threadIdx.x;
    float m = -3.4e38f;
    for (int i = tid; i < N_NODES; i += 1024) m = fmaxf(m, scores[i]);
    sm[tid] = m; __syncthreads();
    for (int s = 512; s > 0; s >>= 1) {
        if (tid < s) sm[tid] = fmaxf(sm[tid], sm[tid + s]);
        __syncthreads();
    }
    m = sm[0];
    __syncthreads();
    float acc = 0.f;
    for (int i = tid; i < N_NODES; i += 1024) acc += expf(scores[i] - m);
    sm[tid] = acc; __syncthreads();
    for (int s = 512; s > 0; s >>= 1) {
        if (tid < s) sm[tid] += sm[tid + s];
        __syncthreads();
    }
    if (tid == 0) { red[0] = m; red[1] = sm[0]; }
}

// ---------------------------------------------------------------------------
// K3: attn = softmax(scores); wfT(bf16, transposed [32][16384]); gc = sum(wf)
// ---------------------------------------------------------------------------
__global__ __launch_bounds__(256) void k_attn_wf(
    const float* __restrict__ scores, const float* __restrict__ red,
    const float* __restrict__ x, float* __restrict__ attn,
    unsigned short* __restrict__ wfT, float* __restrict__ gc)
{
    const int n = blockIdx.x * 256 + threadIdx.x;
    const float m = red[0], s = red[1];
    const float a = expf(scores[n] - m) / s;
    attn[n] = a;

    float wv[32];
    const float4* xr = (const float4*)(x + (size_t)n * 32);
    #pragma unroll
    for (int q = 0; q < 8; ++q) {
        float4 v = xr[q];
        wv[q*4+0] = v.x * a; wv[q*4+1] = v.y * a;
        wv[q*4+2] = v.z * a; wv[q*4+3] = v.w * a;
    }
    #pragma unroll
    for (int c = 0; c < 32; ++c)
        wfT[(size_t)c * N_NODES + n] = f2bf(wv[c]);   // coalesced per c

    const int lane = threadIdx.x & 63;
    #pragma unroll
    for (int c = 0; c < 32; ++c) {
        float v = wv[c];
        v += __shfl_xor(v, 1);  v += __shfl_xor(v, 2);  v += __shfl_xor(v, 4);
        v += __shfl_xor(v, 8);  v += __shfl_xor(v, 16); v += __shfl_xor(v, 32);
        if (lane == 0) atomicAdd(&gc[c], v);
    }
}

// ---------------------------------------------------------------------------
// K5 v7: same bulk structure as v6, but blockIdx mapping puts the COLUMN
// SLAB in the LOW bits: js = bid & 63, rb = bid >> 6. Co-resident blocks
// then span all 64 column slabs -> A-row reads cover all HBM channel
// offsets (mod 64KB) simultaneously, fixing the channel aliasing that
// capped the stream at ~4.4 TB/s (all prior versions kept ~3 slabs
// resident; every 64KB-strided row hit the same channel subset).
// ---------------------------------------------------------------------------
__global__ __launch_bounds__(256, 3) void k_context(
    const float* __restrict__ A, const unsigned short* __restrict__ wfT,
    const float* __restrict__ x, const float* __restrict__ attn,
    float* __restrict__ partials)
{
    __shared__ unsigned short sB_u[32 * 256];    // 16 KB, XOR-swizzled
    __shared__ short sA[4][16 * 256];            // 32 KB: per-wave 16 rows x 256
    __shared__ float sRed[4];

    const int tid   = threadIdx.x;
    const int wid   = tid >> 6, lane = tid & 63;
    const int js    = blockIdx.x & 63;    // 64 col-splits of 256  (LOW bits)
    const int rb    = blockIdx.x >> 6;    // 256 row-blocks of 64 rows
    const int i0    = rb * 64 + wid * 16;
    const int gcol0 = js * 256;

    const int q   = lane >> 4;
    const int r16 = lane & 15;
    char* wbase = (char*)sA[wid];

    // ---- issue A loads FIRST: 16 instructions, each one full row = 1KB ----
    f4v av[16];
    #pragma unroll
    for (int r = 0; r < 16; ++r)
        av[r] = __builtin_nontemporal_load(
            (const f4v*)(A + (size_t)(i0 + r) * N_NODES + gcol0 + lane * 4));

    // ---- stage B slice (L2-resident wfT): 32 rows x 512B, swizzled ----
    {
        const int row = tid >> 3;                 // 0..31
        const unsigned short* gB = wfT + (size_t)row * N_NODES + gcol0;
        char* lB = (char*)sB_u + row * 512;
        #pragma unroll
        for (int c = 0; c < 4; ++c) {
            const int chunk = (tid & 7) + 8 * c;  // 0..31, 16B each
            short8 v = *(const short8*)(gB + chunk * 8);
            *(short8*)(lB + ((chunk * 16) ^ ((row & 7) << 4))) = v;
        }
    }
    __syncthreads();   // B visible to all waves (also implies vmcnt drain of A)

    // ---- cvt + write A rows into wave-private LDS (8B/lane, swizzled) ----
    #pragma unroll
    for (int r = 0; r < 16; ++r) {
        s16x4 w;
        w[0] = (short)f2bf(av[r][0]); w[1] = (short)f2bf(av[r][1]);
        w[2] = (short)f2bf(av[r][2]); w[3] = (short)f2bf(av[r][3]);
        *(s16x4*)(wbase + r * 512 + ((lane * 8) ^ ((r & 7) << 4))) = w;
    }

    // ---- MFMA: 8 k-slices x 2 channel-halves (wave-private A, shared B) ----
    f32x4 acc0 = {0.f, 0.f, 0.f, 0.f};
    f32x4 acc1 = {0.f, 0.f, 0.f, 0.f};
    const int swzA = (r16 & 7) << 4;
    const char* sBb = (const char*)sB_u;
    #pragma unroll
    for (int kk = 0; kk < 8; ++kk) {
        const int fo = kk * 64 + q * 16;
        short8 afr = *(const short8*)(wbase + r16 * 512 + (fo ^ swzA));
        short8 b0  = *(const short8*)(sBb + r16 * 512        + (fo ^ swzA));
        short8 b1  = *(const short8*)(sBb + (r16 + 16) * 512 + (fo ^ swzA));
        // (r16+16)&7 == r16&7 (16 ≡ 0 mod 8) -> same swizzle key for both B rows
        acc0 = __builtin_amdgcn_mfma_f32_16x16x32_bf16(afr, b0, acc0, 0, 0, 0);
        acc1 = __builtin_amdgcn_mfma_f32_16x16x32_bf16(afr, b1, acc1, 0, 0, 0);
    }

    // ---- epilogue: D[row=q*4+r, col=r16]; dot with wf = x*attn, reduce ----
    float partial = 0.f;
    #pragma unroll
    for (int r = 0; r < 4; ++r) {
        const int i = i0 + q * 4 + r;
        const float a = attn[i];
        partial += acc0[r] * (x[(size_t)i * 32 + r16]      * a);
        partial += acc1[r] * (x[(size_t)i * 32 + 16 + r16] * a);
    }
    partial += __shfl_xor(partial, 1);  partial += __shfl_xor(partial, 2);
    partial += __shfl_xor(partial, 4);  partial += __shfl_xor(partial, 8);
    partial += __shfl_xor(partial, 16); partial += __shfl_xor(partial, 32);
    if (lane == 0) sRed[wid] = partial;
    __syncthreads();
    if (tid == 0) partials[blockIdx.x] = (sRed[0] + sRed[1]) + (sRed[2] + sRed[3]);
}

// ---------------------------------------------------------------------------
// K6a: reduce partials[16384] -> cs; h1 for gc and gc2 = gc + 0.001*(cs/N)
// ---------------------------------------------------------------------------
__global__ __launch_bounds__(1024) void k_mlp1(
    const float* __restrict__ gc, const float* __restrict__ partials,
    const float* __restrict__ w1, const float* __restrict__ b1,
    float* __restrict__ h1ab)
{
    __shared__ float sm[1024];
    __shared__ float g1[32], g2[32];
    const int t = threadIdx.x;
    float acc = 0.f;
    #pragma unroll
    for (int i = 0; i < 16; ++i) acc += partials[t + 1024 * i];
    sm[t] = acc; __syncthreads();
    for (int s = 512; s > 0; s >>= 1) {
        if (t < s) sm[t] += sm[t + s];
        __syncthreads();
    }
    if (t < 32) {
        float cs = sm[0] * (1.0f / 16384.0f);
        g1[t] = gc[t];
        g2[t] = gc[t] + 0.001f * cs;
    }
    __syncthreads();
    float s1 = b1[t], s2 = b1[t];
    #pragma unroll
    for (int c = 0; c < 32; ++c) {
        float wv = w1[(size_t)c * 1024 + t];
        s1 += g1[c] * wv;
        s2 += g2[c] * wv;
    }
    h1ab[t]        = fmaxf(s1, 0.f);
    h1ab[1024 + t] = fmaxf(s2, 0.f);
}

// ---------------------------------------------------------------------------
// K6b: h2 = relu(h1 @ w2 + b2), split-K (16 K-groups of 64), LDS tree reduce.
// ---------------------------------------------------------------------------
__global__ __launch_bounds__(256) void k_mlp2(
    const float* __restrict__ h1ab, const float* __restrict__ w2,
    const float* __restrict__ b2, float* __restrict__ h2ab)
{
    __shared__ float h1s[1024];
    __shared__ float sm[256];
    const int v   = blockIdx.x & 1;
    const int ob  = blockIdx.x >> 1;      // 0..63
    const int tid = threadIdx.x;
    const int o   = tid & 15, g = tid >> 4;
    for (int i = tid; i < 1024; i += 256) h1s[i] = h1ab[v * 1024 + i];
    __syncthreads();
    const float* wp = w2 + (size_t)(g * 64) * 1024 + ob * 16 + o;
    float acc = 0.f;
    #pragma unroll 8
    for (int k = 0; k < 64; ++k)
        acc += h1s[g * 64 + k] * wp[(size_t)k * 1024];
    sm[tid] = acc;
    __syncthreads();
    if (tid < 16) {
        float s = b2[ob * 16 + tid];
        #pragma unroll
        for (int g2 = 0; g2 < 16; ++g2) s += sm[g2 * 16 + tid];
        h2ab[v * 1024 + ob * 16 + tid] = fmaxf(s, 0.f);
    }
}

// ---------------------------------------------------------------------------
// K6c: out = relu(h2a@w3+b3) + 0.002*relu(h2b@w3+b3), split-K, both variants.
// ---------------------------------------------------------------------------
__global__ __launch_bounds__(512) void k_mlp3(
    const float* __restrict__ h2ab, const float* __restrict__ w3,
    const float* __restrict__ b3, float* __restrict__ out)
{
    __shared__ float sm[512];
    const int tid = threadIdx.x;
    const int v   = tid >> 8;
    const int g   = (tid >> 4) & 15;
    const int o   = tid & 15;
    const int ob  = blockIdx.x;           // 16 blocks x 16 outputs
    const float* hp = h2ab + v * 1024 + g * 64;
    const float* wp = w3 + (size_t)(g * 64) * 256 + ob * 16 + o;
    float acc = 0.f;
    #pragma unroll 8
    for (int k = 0; k < 64; ++k)
        acc += hp[k] * wp[(size_t)k * 256];
    sm[tid] = acc;
    __syncthreads();
    if (tid < 16) {
        float pa = b3[ob * 16 + tid], pb = pa;
        #pragma unroll
        for (int g2 = 0; g2 < 16; ++g2) {
            pa += sm[g2 * 16 + tid];
            pb += sm[256 + g2 * 16 + tid];
        }
        out[ob * 16 + tid] = fmaxf(pa, 0.f) + 0.002f * fmaxf(pb, 0.f);
    }
}

// ---------------------------------------------------------------------------
extern "C" void kernel_launch(void* const* d_in, const int* in_sizes, int n_in,
                              void* d_out, int out_size, void* d_ws, size_t ws_size,
                              hipStream_t stream)
{
    const float* x   = (const float*)d_in[0];
    const float* A   = (const float*)d_in[1];
    const float* gw1 = (const float*)d_in[2];
    const float* gb1 = (const float*)d_in[3];
    const float* gw2 = (const float*)d_in[4];
    const float* gb2 = (const float*)d_in[5];
    const float* gw3 = (const float*)d_in[6];
    const float* gb3 = (const float*)d_in[7];
    const float* aw1 = (const float*)d_in[8];
    const float* ab1 = (const float*)d_in[9];
    const float* aw2 = (const float*)d_in[10];
    const float* ab2 = (const float*)d_in[11];
    const float* aw3 = (const float*)d_in[12];
    const float* ab3 = (const float*)d_in[13];
    float* out = (float*)d_out;

    char* ws = (char*)d_ws;
    float* scores   = (float*)(ws + 0);            // 16384 f32
    float* attn     = (float*)(ws + 65536);        // 16384 f32
    float* red      = (float*)(ws + 131072);       // 2 f32 (max, sumexp)
    float* gc       = (float*)(ws + 131328);       // 32 f32
    float* h1ab     = (float*)(ws + 131584);       // 2048 f32
    float* h2ab     = (float*)(ws + 139776);       // 2048 f32
    float* partials = (float*)(ws + 163840);       // 16384 f32 (ends 229376)
    unsigned short* wfT = (unsigned short*)(ws + 262144);  // 32*16384 bf16 = 1 MB

    k_zero       <<<1,    32,   0, stream>>>(gc);
    k_attn_scores<<<N_NODES/8, 256, 0, stream>>>(x, aw1, ab1, aw2, ab2, aw3, ab3, scores);
    k_softmax_red<<<1,    1024, 0, stream>>>(scores, red);
    k_attn_wf    <<<N_NODES/256, 256, 0, stream>>>(scores, red, x, attn, wfT, gc);
    k_context    <<<16384, 256, 0, stream>>>(A, wfT, x, attn, partials);
    k_mlp1       <<<1,    1024, 0, stream>>>(gc, partials, gw1, gb1, h1ab);
    k_mlp2       <<<128,  256,  0, stream>>>(h1ab, gw2, gb2, h2ab);
    k_mlp3       <<<16,   512,  0, stream>>>(h2ab, gw3, gb3, out);
}